// Round 1
// baseline (499.614 us; speedup 1.0000x reference)
//
#include <hip/hip_runtime.h>
#include <type_traits>

#define S_LEN 2048
#define NHEAD 16
#define DHEAD 64
#define EMB   1024
#define NBATCH 2

typedef __bf16 bf16_t;
typedef bf16_t bf16x8 __attribute__((ext_vector_type(8)));
typedef float  f32x4  __attribute__((ext_vector_type(4)));
typedef unsigned short us_t;
typedef us_t   us8    __attribute__((ext_vector_type(8)));

static __device__ __forceinline__ bf16x8 ld_bf16x8(const us_t* p) {
  return __builtin_bit_cast(bf16x8, *reinterpret_cast<const us8*>(p));
}
static __device__ __forceinline__ us_t f2bf(float f) {
  bf16_t h = (bf16_t)f;
  return __builtin_bit_cast(us_t, h);
}

// ---------------- weight transpose + fp32->bf16 convert ----------------
// W: fp32 [K=1024][N=1024]  ->  WT: bf16 [N][K]
__global__ __launch_bounds__(256) void wtrans(const float* __restrict__ W,
                                              us_t* __restrict__ WT) {
  __shared__ float tile[32][33];
  const int n0 = blockIdx.x * 32, k0 = blockIdx.y * 32;
  const int tx = threadIdx.x & 31, ty = threadIdx.x >> 5;  // ty in 0..7
#pragma unroll
  for (int i = 0; i < 32; i += 8)
    tile[ty + i][tx] = W[(size_t)(k0 + ty + i) * EMB + n0 + tx];
  __syncthreads();
#pragma unroll
  for (int i = 0; i < 32; i += 8)
    WT[(size_t)(n0 + ty + i) * EMB + k0 + tx] = f2bf(tile[tx][ty + i]);
}

// ---------------- GEMM: X[M,1024] @ W[1024,1024] (W given transposed bf16) ----
// MODE 0: out bf16 at [(b*16+h)][s][d]   (Q/K projection)
// MODE 1: out bf16 at [(b*16+h)][d][s]   (V projection, transposed per head)
// MODE 2: out fp32 at [m][n]             (final output)
template<int MODE, typename AT>
__global__ __launch_bounds__(256) void gemm128(const AT* __restrict__ A,
                                               const us_t* __restrict__ BT,
                                               void* __restrict__ outp) {
  const int lane = threadIdx.x & 63;
  const int wave = threadIdx.x >> 6;
  const int m0 = blockIdx.y * 128 + (wave >> 1) * 64;
  const int n0 = blockIdx.x * 128 + (wave & 1) * 64;
  const int lr  = lane & 15;
  const int lko = (lane >> 4) * 8;

  f32x4 acc[4][4] = {};

  for (int k0 = 0; k0 < EMB; k0 += 32) {
    bf16x8 af[4], bfr[4];
#pragma unroll
    for (int i = 0; i < 4; ++i) {
      if constexpr (std::is_same_v<AT, float>) {
        const float* ap = A + (size_t)(m0 + 16 * i + lr) * EMB + k0 + lko;
        f32x4 lo = *reinterpret_cast<const f32x4*>(ap);
        f32x4 hi = *reinterpret_cast<const f32x4*>(ap + 4);
        bf16x8 t;
#pragma unroll
        for (int j = 0; j < 4; ++j) { t[j] = (bf16_t)lo[j]; t[j + 4] = (bf16_t)hi[j]; }
        af[i] = t;
      } else {
        af[i] = ld_bf16x8(A + (size_t)(m0 + 16 * i + lr) * EMB + k0 + lko);
      }
      bfr[i] = ld_bf16x8(BT + (size_t)(n0 + 16 * i + lr) * EMB + k0 + lko);
    }
#pragma unroll
    for (int i = 0; i < 4; ++i)
#pragma unroll
      for (int j = 0; j < 4; ++j)
        acc[i][j] = __builtin_amdgcn_mfma_f32_16x16x32_bf16(af[i], bfr[j], acc[i][j], 0, 0, 0);
  }

  const int crow = (lane >> 4) * 4;
  const int ccol = lane & 15;
#pragma unroll
  for (int i = 0; i < 4; ++i)
#pragma unroll
    for (int j = 0; j < 4; ++j)
#pragma unroll
      for (int r = 0; r < 4; ++r) {
        const int m = m0 + 16 * i + crow + r;
        const int n = n0 + 16 * j + ccol;
        const float val = acc[i][j][r];
        if constexpr (MODE == 0) {
          us_t* o = (us_t*)outp;
          const int b = m >> 11, s = m & (S_LEN - 1);
          const int h = n >> 6, d = n & 63;
          o[(((size_t)(b * NHEAD + h) * S_LEN + s) << 6) + d] = f2bf(val);
        } else if constexpr (MODE == 1) {
          us_t* o = (us_t*)outp;
          const int b = m >> 11, s = m & (S_LEN - 1);
          const int h = n >> 6, d = n & 63;
          o[((size_t)(b * NHEAD + h) * DHEAD + d) * S_LEN + s] = f2bf(val);
        } else {
          float* o = (float*)outp;
          o[(size_t)m * EMB + n] = val;
        }
      }
}

// ---------------- flash attention (strictly-causal + [0,0] exception) -------
// Qh,Kh: bf16 [B*H][S][64]; Vt: bf16 [B*H][64][S]; AO: bf16 [B][S][H*64]
__global__ __launch_bounds__(256) void attn64(const us_t* __restrict__ Qh,
                                              const us_t* __restrict__ Kh,
                                              const us_t* __restrict__ Vt,
                                              us_t* __restrict__ AO) {
  __shared__ us_t Plds[4][16][80];   // per-wave P tile, padded rows
  const int qt = blockIdx.x;         // q tile (64 rows)
  const int bh = blockIdx.y;         // b*16+h
  const int lane = threadIdx.x & 63;
  const int wave = threadIdx.x >> 6;
  const int lr = lane & 15;
  const int lg = lane >> 4;          // 0..3
  const int q0 = qt * 64 + wave * 16;

  const us_t* qbase = Qh + ((size_t)bh * S_LEN + q0 + lr) * DHEAD;
  bf16x8 qf[2] = { ld_bf16x8(qbase + lg * 8), ld_bf16x8(qbase + 32 + lg * 8) };

  f32x4 oacc[4] = {};
  float mrow[4], lsum[4];
#pragma unroll
  for (int r = 0; r < 4; ++r) { mrow[r] = -1e30f; lsum[r] = 0.f; }

  for (int tt = 0; tt <= qt; ++tt) {
    // ---- scores S = Q K^T * scale ----
    f32x4 sc[4] = {};
    const us_t* kbase = Kh + ((size_t)bh * S_LEN + tt * 64) * DHEAD;
#pragma unroll
    for (int ks = 0; ks < 2; ++ks) {
#pragma unroll
      for (int j = 0; j < 4; ++j) {
        bf16x8 bk = ld_bf16x8(kbase + (size_t)(16 * j + lr) * DHEAD + ks * 32 + lg * 8);
        sc[j] = __builtin_amdgcn_mfma_f32_16x16x32_bf16(qf[ks], bk, sc[j], 0, 0, 0);
      }
    }
    const bool diag = (tt == qt);
#pragma unroll
    for (int j = 0; j < 4; ++j)
#pragma unroll
      for (int r = 0; r < 4; ++r) {
        float s = sc[j][r] * 0.03125f;   // 1/sqrt(1024)
        if (diag) {
          const int qq = q0 + lg * 4 + r;
          const int tc = tt * 64 + 16 * j + lr;
          if (!((tc < qq) || (qq == 0 && tc == 0))) s = -1e30f;
        }
        sc[j][r] = s;
      }
    // ---- online softmax (rows live across 16-lane groups) ----
#pragma unroll
    for (int r = 0; r < 4; ++r) {
      float mx = fmaxf(fmaxf(sc[0][r], sc[1][r]), fmaxf(sc[2][r], sc[3][r]));
#pragma unroll
      for (int off = 1; off < 16; off <<= 1)
        mx = fmaxf(mx, __shfl_xor(mx, off, 64));
      const float mnew = fmaxf(mrow[r], mx);
      const float alpha = __expf(mrow[r] - mnew);
      float psum = 0.f;
#pragma unroll
      for (int j = 0; j < 4; ++j) {
        const float p = __expf(sc[j][r] - mnew);
        sc[j][r] = p;
        psum += p;
      }
#pragma unroll
      for (int off = 1; off < 16; off <<= 1)
        psum += __shfl_xor(psum, off, 64);
      lsum[r] = lsum[r] * alpha + psum;
      mrow[r] = mnew;
#pragma unroll
      for (int jd = 0; jd < 4; ++jd) oacc[jd][r] *= alpha;
    }
    // ---- P (C-layout) -> LDS -> A-layout for PV ----
#pragma unroll
    for (int j = 0; j < 4; ++j)
#pragma unroll
      for (int r = 0; r < 4; ++r)
        Plds[wave][lg * 4 + r][16 * j + lr] = f2bf(sc[j][r]);
    __syncthreads();
    const us_t* vbase = Vt + (size_t)bh * DHEAD * S_LEN + tt * 64;
#pragma unroll
    for (int ks = 0; ks < 2; ++ks) {
      bf16x8 ap = ld_bf16x8(&Plds[wave][lr][ks * 32 + lg * 8]);
#pragma unroll
      for (int j = 0; j < 4; ++j) {
        bf16x8 bv = ld_bf16x8(vbase + (size_t)(16 * j + lr) * S_LEN + ks * 32 + lg * 8);
        oacc[j] = __builtin_amdgcn_mfma_f32_16x16x32_bf16(ap, bv, oacc[j], 0, 0, 0);
      }
    }
    __syncthreads();
  }
  // ---- normalize + store [B][S][H*64] ----
  const int b = bh >> 4, h = bh & 15;
#pragma unroll
  for (int r = 0; r < 4; ++r) {
    const float inv = 1.0f / lsum[r];
    const int qq = q0 + lg * 4 + r;
#pragma unroll
    for (int j = 0; j < 4; ++j)
      AO[(size_t)(b * S_LEN + qq) * EMB + h * DHEAD + 16 * j + lr] =
          f2bf(oacc[j][r] * inv);
  }
}

// ---------------------------------------------------------------------------
extern "C" void kernel_launch(void* const* d_in, const int* in_sizes, int n_in,
                              void* d_out, int out_size, void* d_ws, size_t ws_size,
                              hipStream_t stream) {
  const float* q  = (const float*)d_in[0];
  const float* k  = (const float*)d_in[1];
  const float* v  = (const float*)d_in[2];
  const float* Wq = (const float*)d_in[3];
  const float* Wk = (const float*)d_in[4];
  const float* Wv = (const float*)d_in[5];
  const float* Wo = (const float*)d_in[6];
  float* out = (float*)d_out;

  char* ws = (char*)d_ws;
  const size_t MB = 1024 * 1024;
  us_t* WqT = (us_t*)(ws + 0 * MB);
  us_t* WkT = (us_t*)(ws + 2 * MB);
  us_t* WvT = (us_t*)(ws + 4 * MB);
  us_t* WoT = (us_t*)(ws + 6 * MB);
  us_t* Qh  = (us_t*)(ws + 8 * MB);
  us_t* Kh  = (us_t*)(ws + 16 * MB);
  us_t* Vt  = (us_t*)(ws + 24 * MB);
  us_t* AO  = (us_t*)(ws + 32 * MB);

  dim3 tg(EMB / 32, EMB / 32);
  wtrans<<<tg, 256, 0, stream>>>(Wq, WqT);
  wtrans<<<tg, 256, 0, stream>>>(Wk, WkT);
  wtrans<<<tg, 256, 0, stream>>>(Wv, WvT);
  wtrans<<<tg, 256, 0, stream>>>(Wo, WoT);

  dim3 gg(EMB / 128, (NBATCH * S_LEN) / 128);  // (8, 32)
  gemm128<0, float><<<gg, 256, 0, stream>>>(q, WqT, Qh);
  gemm128<0, float><<<gg, 256, 0, stream>>>(k, WkT, Kh);
  gemm128<1, float><<<gg, 256, 0, stream>>>(v, WvT, Vt);

  attn64<<<dim3(S_LEN / 64, NBATCH * NHEAD), 256, 0, stream>>>(Qh, Kh, Vt, AO);

  gemm128<2, us_t><<<gg, 256, 0, stream>>>(AO, WoT, out);
}

// Round 2
// 429.955 us; speedup vs baseline: 1.1620x; 1.1620x over previous
//
#include <hip/hip_runtime.h>
#include <type_traits>

#define S_LEN 2048
#define NHEAD 16
#define DHEAD 64
#define EMB   1024
#define NBATCH 2

typedef __bf16 bf16_t;
typedef bf16_t bf16x8 __attribute__((ext_vector_type(8)));
typedef float  f32x4  __attribute__((ext_vector_type(4)));
typedef unsigned short us_t;
typedef us_t   us8    __attribute__((ext_vector_type(8)));

static __device__ __forceinline__ bf16x8 ld_bf16x8(const us_t* p) {
  return __builtin_bit_cast(bf16x8, *reinterpret_cast<const us8*>(p));
}
static __device__ __forceinline__ us_t f2bf(float f) {
  bf16_t h = (bf16_t)f;
  return __builtin_bit_cast(us_t, h);
}

// ---------------- weight transpose + fp32->bf16 convert ----------------
// W: fp32 [K=1024][N=1024]  ->  WT: bf16 [N][K]
__global__ __launch_bounds__(256) void wtrans(const float* __restrict__ W,
                                              us_t* __restrict__ WT) {
  __shared__ float tile[32][33];
  const int n0 = blockIdx.x * 32, k0 = blockIdx.y * 32;
  const int tx = threadIdx.x & 31, ty = threadIdx.x >> 5;  // ty in 0..7
#pragma unroll
  for (int i = 0; i < 32; i += 8)
    tile[ty + i][tx] = W[(size_t)(k0 + ty + i) * EMB + n0 + tx];
  __syncthreads();
#pragma unroll
  for (int i = 0; i < 32; i += 8)
    WT[(size_t)(n0 + ty + i) * EMB + k0 + tx] = f2bf(tile[tx][ty + i]);
}

// ---------------- GEMM: X[M,1024] @ W[1024,1024] (W given transposed bf16) ----
// MODE 0: out bf16 at [(b*16+h)][s][d]   (Q/K projection)
// MODE 1: out bf16 at [(b*16+h)][d][s]   (V projection, transposed per head)
// MODE 2: out fp32 at [m][n]             (final output)
template<int MODE, typename AT>
__global__ __launch_bounds__(256) void gemm128(const AT* __restrict__ A,
                                               const us_t* __restrict__ BT,
                                               void* __restrict__ outp) {
  const int lane = threadIdx.x & 63;
  const int wave = threadIdx.x >> 6;
  const int m0 = blockIdx.y * 128 + (wave >> 1) * 64;
  const int n0 = blockIdx.x * 128 + (wave & 1) * 64;
  const int lr  = lane & 15;
  const int lko = (lane >> 4) * 8;

  f32x4 acc[4][4] = {};

  for (int k0 = 0; k0 < EMB; k0 += 32) {
    bf16x8 af[4], bfr[4];
#pragma unroll
    for (int i = 0; i < 4; ++i) {
      if constexpr (std::is_same_v<AT, float>) {
        const float* ap = A + (size_t)(m0 + 16 * i + lr) * EMB + k0 + lko;
        f32x4 lo = *reinterpret_cast<const f32x4*>(ap);
        f32x4 hi = *reinterpret_cast<const f32x4*>(ap + 4);
        bf16x8 t;
#pragma unroll
        for (int j = 0; j < 4; ++j) { t[j] = (bf16_t)lo[j]; t[j + 4] = (bf16_t)hi[j]; }
        af[i] = t;
      } else {
        af[i] = ld_bf16x8(A + (size_t)(m0 + 16 * i + lr) * EMB + k0 + lko);
      }
      bfr[i] = ld_bf16x8(BT + (size_t)(n0 + 16 * i + lr) * EMB + k0 + lko);
    }
#pragma unroll
    for (int i = 0; i < 4; ++i)
#pragma unroll
      for (int j = 0; j < 4; ++j)
        acc[i][j] = __builtin_amdgcn_mfma_f32_16x16x32_bf16(af[i], bfr[j], acc[i][j], 0, 0, 0);
  }

  const int crow = (lane >> 4) * 4;
  const int ccol = lane & 15;
#pragma unroll
  for (int i = 0; i < 4; ++i)
#pragma unroll
    for (int j = 0; j < 4; ++j)
#pragma unroll
      for (int r = 0; r < 4; ++r) {
        const int m = m0 + 16 * i + crow + r;
        const int n = n0 + 16 * j + ccol;
        const float val = acc[i][j][r];
        if constexpr (MODE == 0) {
          us_t* o = (us_t*)outp;
          const int b = m >> 11, s = m & (S_LEN - 1);
          const int h = n >> 6, d = n & 63;
          o[(((size_t)(b * NHEAD + h) * S_LEN + s) << 6) + d] = f2bf(val);
        } else if constexpr (MODE == 1) {
          us_t* o = (us_t*)outp;
          const int b = m >> 11, s = m & (S_LEN - 1);
          const int h = n >> 6, d = n & 63;
          o[((size_t)(b * NHEAD + h) * DHEAD + d) * S_LEN + s] = f2bf(val);
        } else {
          float* o = (float*)outp;
          o[(size_t)m * EMB + n] = val;
        }
      }
}

// ---------------- flash attention (strictly-causal + [0,0] exception) -------
// Qh,Kh: bf16 [B*H][S][64]; Vt: bf16 [B*H][64][S]; AO: bf16 [B][S][H*64]
// No __syncthreads: Plds is strictly per-wave (intra-wave lgkmcnt ordering
// is compiler-inserted). Heavy q-tiles dispatched first (LPT). K/V for the
// next kv-tile are prefetched into the same registers right after last use.
__global__ __launch_bounds__(256) void attn64(const us_t* __restrict__ Qh,
                                              const us_t* __restrict__ Kh,
                                              const us_t* __restrict__ Vt,
                                              us_t* __restrict__ AO) {
  __shared__ us_t Plds[4][16][80];   // per-wave P tile, padded rows
  const int qt = (S_LEN / 64 - 1) - blockIdx.x;  // heavy-first
  const int bh = blockIdx.y;         // b*16+h
  const int lane = threadIdx.x & 63;
  const int wave = threadIdx.x >> 6;
  const int lr = lane & 15;
  const int lg = lane >> 4;          // 0..3
  const int q0 = qt * 64 + wave * 16;

  const us_t* qbase = Qh + ((size_t)bh * S_LEN + q0 + lr) * DHEAD;
  bf16x8 qf[2] = { ld_bf16x8(qbase + lg * 8), ld_bf16x8(qbase + 32 + lg * 8) };

  const us_t* kbase0 = Kh + (size_t)bh * S_LEN * DHEAD;
  const us_t* vbase0 = Vt + (size_t)bh * DHEAD * S_LEN;

  // prologue: load K,V for tile 0
  bf16x8 kf[2][4], vf[2][4];
#pragma unroll
  for (int ks = 0; ks < 2; ++ks)
#pragma unroll
    for (int j = 0; j < 4; ++j) {
      kf[ks][j] = ld_bf16x8(kbase0 + (size_t)(16 * j + lr) * DHEAD + ks * 32 + lg * 8);
      vf[ks][j] = ld_bf16x8(vbase0 + (size_t)(16 * j + lr) * S_LEN + ks * 32 + lg * 8);
    }

  f32x4 oacc[4] = {};
  float mrow[4], lsum[4];
#pragma unroll
  for (int r = 0; r < 4; ++r) { mrow[r] = -1e30f; lsum[r] = 0.f; }

  for (int tt = 0; tt <= qt; ++tt) {
    // ---- scores S = Q K^T ----
    f32x4 sc[4] = {};
#pragma unroll
    for (int ks = 0; ks < 2; ++ks)
#pragma unroll
      for (int j = 0; j < 4; ++j)
        sc[j] = __builtin_amdgcn_mfma_f32_16x16x32_bf16(qf[ks], kf[ks][j], sc[j], 0, 0, 0);

    // ---- prefetch next K tile (kf dead after the MFMAs above) ----
    const int tn = (tt + 1 <= qt) ? (tt + 1) : qt;
    const us_t* kb = kbase0 + (size_t)(tn * 64) * DHEAD;
#pragma unroll
    for (int ks = 0; ks < 2; ++ks)
#pragma unroll
      for (int j = 0; j < 4; ++j)
        kf[ks][j] = ld_bf16x8(kb + (size_t)(16 * j + lr) * DHEAD + ks * 32 + lg * 8);

    // ---- mask + scale ----
    const bool diag = (tt == qt);
#pragma unroll
    for (int j = 0; j < 4; ++j)
#pragma unroll
      for (int r = 0; r < 4; ++r) {
        float s = sc[j][r] * 0.03125f;   // 1/sqrt(1024)
        if (diag) {
          const int qq = q0 + lg * 4 + r;
          const int tc = tt * 64 + 16 * j + lr;
          if (!((tc < qq) || (qq == 0 && tc == 0))) s = -1e30f;
        }
        sc[j][r] = s;
      }
    // ---- online softmax (rows live across 16-lane groups) ----
#pragma unroll
    for (int r = 0; r < 4; ++r) {
      float mx = fmaxf(fmaxf(sc[0][r], sc[1][r]), fmaxf(sc[2][r], sc[3][r]));
#pragma unroll
      for (int off = 1; off < 16; off <<= 1)
        mx = fmaxf(mx, __shfl_xor(mx, off, 64));
      const float mnew = fmaxf(mrow[r], mx);
      const float alpha = __expf(mrow[r] - mnew);
      float psum = 0.f;
#pragma unroll
      for (int j = 0; j < 4; ++j) {
        const float p = __expf(sc[j][r] - mnew);
        sc[j][r] = p;
        psum += p;
      }
#pragma unroll
      for (int off = 1; off < 16; off <<= 1)
        psum += __shfl_xor(psum, off, 64);
      lsum[r] = lsum[r] * alpha + psum;
      mrow[r] = mnew;
#pragma unroll
      for (int jd = 0; jd < 4; ++jd) oacc[jd][r] *= alpha;
    }
    // ---- P (C-layout) -> per-wave LDS -> A-layout for PV (no barrier) ----
#pragma unroll
    for (int j = 0; j < 4; ++j)
#pragma unroll
      for (int r = 0; r < 4; ++r)
        Plds[wave][lg * 4 + r][16 * j + lr] = f2bf(sc[j][r]);
#pragma unroll
    for (int ks = 0; ks < 2; ++ks) {
      bf16x8 ap = ld_bf16x8(&Plds[wave][lr][ks * 32 + lg * 8]);
#pragma unroll
      for (int j = 0; j < 4; ++j)
        oacc[j] = __builtin_amdgcn_mfma_f32_16x16x32_bf16(ap, vf[ks][j], oacc[j], 0, 0, 0);
    }
    // ---- prefetch next V tile (vf dead after the MFMAs above) ----
    const us_t* vb = vbase0 + tn * 64;
#pragma unroll
    for (int ks = 0; ks < 2; ++ks)
#pragma unroll
      for (int j = 0; j < 4; ++j)
        vf[ks][j] = ld_bf16x8(vb + (size_t)(16 * j + lr) * S_LEN + ks * 32 + lg * 8);
  }
  // ---- normalize + store [B][S][H*64] ----
  const int b = bh >> 4, h = bh & 15;
#pragma unroll
  for (int r = 0; r < 4; ++r) {
    const float inv = 1.0f / lsum[r];
    const int qq = q0 + lg * 4 + r;
#pragma unroll
    for (int j = 0; j < 4; ++j)
      AO[(size_t)(b * S_LEN + qq) * EMB + h * DHEAD + 16 * j + lr] =
          f2bf(oacc[j][r] * inv);
  }
}

// ---------------------------------------------------------------------------
extern "C" void kernel_launch(void* const* d_in, const int* in_sizes, int n_in,
                              void* d_out, int out_size, void* d_ws, size_t ws_size,
                              hipStream_t stream) {
  const float* q  = (const float*)d_in[0];
  const float* k  = (const float*)d_in[1];
  const float* v  = (const float*)d_in[2];
  const float* Wq = (const float*)d_in[3];
  const float* Wk = (const float*)d_in[4];
  const float* Wv = (const float*)d_in[5];
  const float* Wo = (const float*)d_in[6];
  float* out = (float*)d_out;

  char* ws = (char*)d_ws;
  const size_t MB = 1024 * 1024;
  us_t* WqT = (us_t*)(ws + 0 * MB);
  us_t* WkT = (us_t*)(ws + 2 * MB);
  us_t* WvT = (us_t*)(ws + 4 * MB);
  us_t* WoT = (us_t*)(ws + 6 * MB);
  us_t* Qh  = (us_t*)(ws + 8 * MB);
  us_t* Kh  = (us_t*)(ws + 16 * MB);
  us_t* Vt  = (us_t*)(ws + 24 * MB);
  us_t* AO  = (us_t*)(ws + 32 * MB);

  dim3 tg(EMB / 32, EMB / 32);
  wtrans<<<tg, 256, 0, stream>>>(Wq, WqT);
  wtrans<<<tg, 256, 0, stream>>>(Wk, WkT);
  wtrans<<<tg, 256, 0, stream>>>(Wv, WvT);
  wtrans<<<tg, 256, 0, stream>>>(Wo, WoT);

  dim3 gg(EMB / 128, (NBATCH * S_LEN) / 128);  // (8, 32)
  gemm128<0, float><<<gg, 256, 0, stream>>>(q, WqT, Qh);
  gemm128<0, float><<<gg, 256, 0, stream>>>(k, WkT, Kh);
  gemm128<1, float><<<gg, 256, 0, stream>>>(v, WvT, Vt);

  attn64<<<dim3(S_LEN / 64, NBATCH * NHEAD), 256, 0, stream>>>(Qh, Kh, Vt, AO);

  gemm128<2, us_t><<<gg, 256, 0, stream>>>(AO, WoT, out);
}

// Round 3
// 184.546 us; speedup vs baseline: 2.7073x; 2.3298x over previous
//
#include <hip/hip_runtime.h>
#include <type_traits>

#define S_LEN 2048
#define NHEAD 16
#define DHEAD 64
#define EMB   1024
#define NBATCH 2

typedef __bf16 bf16_t;
typedef bf16_t bf16x8 __attribute__((ext_vector_type(8)));
typedef float  f32x4  __attribute__((ext_vector_type(4)));
typedef unsigned short us_t;
typedef us_t   us8    __attribute__((ext_vector_type(8)));

static __device__ __forceinline__ bf16x8 ld_bf16x8(const us_t* p) {
  return __builtin_bit_cast(bf16x8, *reinterpret_cast<const us8*>(p));
}
static __device__ __forceinline__ us_t f2bf(float f) {
  bf16_t h = (bf16_t)f;
  return __builtin_bit_cast(us_t, h);
}
// async global->LDS, 16B per lane. LDS dest = wave-uniform base + lane*16.
static __device__ __forceinline__ void gload16(const void* g, void* lds) {
  __builtin_amdgcn_global_load_lds((const __attribute__((address_space(1))) void*)g,
                                   (__attribute__((address_space(3))) void*)lds,
                                   16, 0, 0);
}

// ---------------- weight transpose + fp32->bf16 convert ----------------
// W: fp32 [K=1024][N=1024]  ->  WT: bf16 [N][K]
__global__ __launch_bounds__(256) void wtrans(const float* __restrict__ W,
                                              us_t* __restrict__ WT) {
  __shared__ float tile[32][33];
  const int n0 = blockIdx.x * 32, k0 = blockIdx.y * 32;
  const int tx = threadIdx.x & 31, ty = threadIdx.x >> 5;
#pragma unroll
  for (int i = 0; i < 32; i += 8)
    tile[ty + i][tx] = W[(size_t)(k0 + ty + i) * EMB + n0 + tx];
  __syncthreads();
#pragma unroll
  for (int i = 0; i < 32; i += 8)
    WT[(size_t)(n0 + ty + i) * EMB + k0 + tx] = f2bf(tile[tx][ty + i]);
}

// ---------------- staged GEMM: X[M,1024] @ W (W transposed bf16) -----------
// 64x128 tile, BK=32, 4 waves (2x2), global_load_lds double-buffered.
// fp32 A staged raw with 16B-granule XOR swizzle (128B rows), cvt on read.
// MODE 0: out bf16 [(b*16+h)][s][d]; MODE 1: out bf16 [(b*16+h)][d][s];
// MODE 2: out fp32 [m][n].
template<int MODE, typename AT>
__global__ __launch_bounds__(256) void gemm64(const AT* __restrict__ A,
                                              const us_t* __restrict__ BT,
                                              void* __restrict__ outp) {
  constexpr bool AF32 = std::is_same_v<AT, float>;
  constexpr int ABYTES = AF32 ? 8192 : 4096;
  __shared__ char As[2][ABYTES];
  __shared__ char Bs[2][8192];
  const int lane = threadIdx.x & 63;
  const int wave = threadIdx.x >> 6;
  const int mt = blockIdx.y * 64;
  const int nt = blockIdx.x * 128;
  const int wm = ((wave >> 1) & 1) * 32;
  const int wn = (wave & 1) * 64;
  const int lr = lane & 15;
  const int lg = lane >> 4;

  f32x4 acc[2][4] = {};

  auto stage = [&](int buf, int k0) {
    if constexpr (AF32) {
      // A tile 64 rows x 128B, swizzled: logical c16 = (l&7)^(l>>3)
#pragma unroll
      for (int i = 0; i < 2; ++i) {
        const int seg = wave * 2 + i;
        const int r = seg * 8 + (lane >> 3);
        const int c16 = (lane & 7) ^ (lane >> 3);
        gload16((const char*)A + ((size_t)(mt + r) * EMB + k0) * 4 + c16 * 16,
                &As[buf][seg * 1024]);
      }
    } else {
      // A tile 64 rows x 64B, linear (bank-balanced for b128 reads)
      const int r = wave * 16 + (lane >> 2);
      gload16((const char*)A + ((size_t)(mt + r) * EMB + k0) * 2 + (lane & 3) * 16,
              &As[buf][wave * 1024]);
    }
#pragma unroll
    for (int i = 0; i < 2; ++i) {
      const int seg = wave * 2 + i;
      const int r = seg * 16 + (lane >> 2);
      gload16((const char*)BT + ((size_t)(nt + r) * EMB + k0) * 2 + (lane & 3) * 16,
              &Bs[buf][seg * 1024]);
    }
  };

  stage(0, 0);
  __syncthreads();

  for (int ks = 0; ks < EMB / 32; ++ks) {
    const int cur = ks & 1;
    if (ks + 1 < EMB / 32) stage(cur ^ 1, (ks + 1) * 32);
    bf16x8 af[2], bfr[4];
#pragma unroll
    for (int i = 0; i < 2; ++i) {
      const int row = wm + 16 * i + lr;
      if constexpr (AF32) {
        const char* rb = &As[cur][row * 128];
        f32x4 lo = *reinterpret_cast<const f32x4*>(rb + ((lg * 32) ^ ((lr & 7) << 4)));
        f32x4 hi = *reinterpret_cast<const f32x4*>(rb + ((lg * 32 + 16) ^ ((lr & 7) << 4)));
        bf16x8 t;
#pragma unroll
        for (int jj = 0; jj < 4; ++jj) { t[jj] = (bf16_t)lo[jj]; t[jj + 4] = (bf16_t)hi[jj]; }
        af[i] = t;
      } else {
        af[i] = ld_bf16x8((const us_t*)&As[cur][row * 64 + lg * 16]);
      }
    }
#pragma unroll
    for (int j = 0; j < 4; ++j)
      bfr[j] = ld_bf16x8((const us_t*)&Bs[cur][(wn + 16 * j + lr) * 64 + lg * 16]);
#pragma unroll
    for (int i = 0; i < 2; ++i)
#pragma unroll
      for (int j = 0; j < 4; ++j)
        acc[i][j] = __builtin_amdgcn_mfma_f32_16x16x32_bf16(af[i], bfr[j], acc[i][j], 0, 0, 0);
    __syncthreads();
  }

  const int crow = (lane >> 4) * 4;
#pragma unroll
  for (int i = 0; i < 2; ++i)
#pragma unroll
    for (int j = 0; j < 4; ++j)
#pragma unroll
      for (int r = 0; r < 4; ++r) {
        const int m = mt + wm + 16 * i + crow + r;
        const int n = nt + wn + 16 * j + lr;
        const float val = acc[i][j][r];
        if constexpr (MODE == 0) {
          us_t* o = (us_t*)outp;
          const int b = m >> 11, s = m & (S_LEN - 1);
          const int h = n >> 6, d = n & 63;
          o[(((size_t)(b * NHEAD + h) * S_LEN + s) << 6) + d] = f2bf(val);
        } else if constexpr (MODE == 1) {
          us_t* o = (us_t*)outp;
          const int b = m >> 11, s = m & (S_LEN - 1);
          const int h = n >> 6, d = n & 63;
          o[((size_t)(b * NHEAD + h) * DHEAD + d) * S_LEN + s] = f2bf(val);
        } else {
          float* o = (float*)outp;
          o[(size_t)m * EMB + n] = val;
        }
      }
}

// ---------------- flash attention (strictly-causal + [0,0] exception) -------
// Qh,Kh: bf16 [B*H][S][64]; Vt: bf16 [B*H][64][S]; AO: bf16 [B][S][H*64]
// Block-level LDS staging of K and V^T tiles (global_load_lds, coalesced,
// XOR-swizzled), double-buffered, one barrier/iter. XCD-aware remap keeps
// all q-tiles of a head on one XCD (2MB K+V per XCD -> L2-resident); LPT.
__global__ __launch_bounds__(256) void attn64(const us_t* __restrict__ Qh,
                                              const us_t* __restrict__ Kh,
                                              const us_t* __restrict__ Vt,
                                              us_t* __restrict__ AO) {
  __shared__ char Ks[2][8192];
  __shared__ char Vs[2][8192];
  __shared__ us_t Plds[4][16][80];
  const int flat = blockIdx.y * 32 + blockIdx.x;
  const int bh = (flat & 7) * 4 + ((flat >> 3) & 3);   // same bh -> same XCD
  const int qt = 31 - (flat >> 5);                     // heavy-first
  const int lane = threadIdx.x & 63;
  const int wave = threadIdx.x >> 6;
  const int lr = lane & 15;
  const int lg = lane >> 4;
  const int q0 = qt * 64 + wave * 16;

  const us_t* qbase = Qh + ((size_t)bh * S_LEN + q0 + lr) * DHEAD;
  bf16x8 qf[2] = { ld_bf16x8(qbase + lg * 8), ld_bf16x8(qbase + 32 + lg * 8) };

  const us_t* kbase0 = Kh + (size_t)bh * S_LEN * DHEAD;
  const us_t* vbase0 = Vt + (size_t)bh * DHEAD * S_LEN;

  auto stage = [&](int buf, int t0) {
#pragma unroll
    for (int i = 0; i < 2; ++i) {
      const int seg = wave * 2 + i;
      const int r = seg * 8 + (lane >> 3);            // local row (k-row / d-row)
      const int c16 = (lane & 7) ^ (lane >> 3);       // inverse of read swizzle
      gload16(kbase0 + (size_t)(t0 + r) * DHEAD + c16 * 8, &Ks[buf][seg * 1024]);
      gload16(vbase0 + (size_t)r * S_LEN + t0 + c16 * 8, &Vs[buf][seg * 1024]);
    }
  };

  f32x4 oacc[4] = {};
  float mrow[4], lsum[4];
#pragma unroll
  for (int r = 0; r < 4; ++r) { mrow[r] = -1e30f; lsum[r] = 0.f; }

  stage(0, 0);
  __syncthreads();

  for (int tt = 0; tt <= qt; ++tt) {
    const int cur = tt & 1;
    if (tt < qt) stage(cur ^ 1, (tt + 1) * 64);
    // ---- scores S = Q K^T ----
    f32x4 sc[4] = {};
#pragma unroll
    for (int ks = 0; ks < 2; ++ks)
#pragma unroll
      for (int j = 0; j < 4; ++j) {
        const int row = 16 * j + lr;
        bf16x8 bk = ld_bf16x8((const us_t*)&Ks[cur][row * 128 +
                              ((ks * 64 + lg * 16) ^ ((lr & 7) << 4))]);
        sc[j] = __builtin_amdgcn_mfma_f32_16x16x32_bf16(qf[ks], bk, sc[j], 0, 0, 0);
      }
    // ---- mask + scale ----
    const bool diag = (tt == qt);
#pragma unroll
    for (int j = 0; j < 4; ++j)
#pragma unroll
      for (int r = 0; r < 4; ++r) {
        float s = sc[j][r] * 0.03125f;   // 1/sqrt(1024)
        if (diag) {
          const int qq = q0 + lg * 4 + r;
          const int tc = tt * 64 + 16 * j + lr;
          if (!((tc < qq) || (qq == 0 && tc == 0))) s = -1e30f;
        }
        sc[j][r] = s;
      }
    // ---- online softmax ----
#pragma unroll
    for (int r = 0; r < 4; ++r) {
      float mx = fmaxf(fmaxf(sc[0][r], sc[1][r]), fmaxf(sc[2][r], sc[3][r]));
#pragma unroll
      for (int off = 1; off < 16; off <<= 1)
        mx = fmaxf(mx, __shfl_xor(mx, off, 64));
      const float mnew = fmaxf(mrow[r], mx);
      const float alpha = __expf(mrow[r] - mnew);
      float psum = 0.f;
#pragma unroll
      for (int j = 0; j < 4; ++j) {
        const float p = __expf(sc[j][r] - mnew);
        sc[j][r] = p;
        psum += p;
      }
#pragma unroll
      for (int off = 1; off < 16; off <<= 1)
        psum += __shfl_xor(psum, off, 64);
      lsum[r] = lsum[r] * alpha + psum;
      mrow[r] = mnew;
#pragma unroll
      for (int jd = 0; jd < 4; ++jd) oacc[jd][r] *= alpha;
    }
    // ---- P (C-layout) -> per-wave LDS -> A-layout ----
#pragma unroll
    for (int j = 0; j < 4; ++j)
#pragma unroll
      for (int r = 0; r < 4; ++r)
        Plds[wave][lg * 4 + r][16 * j + lr] = f2bf(sc[j][r]);
    // ---- PV ----
#pragma unroll
    for (int ks = 0; ks < 2; ++ks) {
      bf16x8 ap = ld_bf16x8(&Plds[wave][lr][ks * 32 + lg * 8]);
#pragma unroll
      for (int j = 0; j < 4; ++j) {
        const int row = 16 * j + lr;
        bf16x8 bv = ld_bf16x8((const us_t*)&Vs[cur][row * 128 +
                              ((ks * 64 + lg * 16) ^ ((lr & 7) << 4))]);
        oacc[j] = __builtin_amdgcn_mfma_f32_16x16x32_bf16(ap, bv, oacc[j], 0, 0, 0);
      }
    }
    __syncthreads();
  }
  // ---- normalize + store [B][S][H*64] ----
  const int b = bh >> 4, h = bh & 15;
#pragma unroll
  for (int r = 0; r < 4; ++r) {
    const float inv = 1.0f / lsum[r];
    const int qq = q0 + lg * 4 + r;
#pragma unroll
    for (int j = 0; j < 4; ++j)
      AO[(size_t)(b * S_LEN + qq) * EMB + h * DHEAD + 16 * j + lr] =
          f2bf(oacc[j][r] * inv);
  }
}

// ---------------------------------------------------------------------------
extern "C" void kernel_launch(void* const* d_in, const int* in_sizes, int n_in,
                              void* d_out, int out_size, void* d_ws, size_t ws_size,
                              hipStream_t stream) {
  const float* q  = (const float*)d_in[0];
  const float* k  = (const float*)d_in[1];
  const float* v  = (const float*)d_in[2];
  const float* Wq = (const float*)d_in[3];
  const float* Wk = (const float*)d_in[4];
  const float* Wv = (const float*)d_in[5];
  const float* Wo = (const float*)d_in[6];
  float* out = (float*)d_out;

  char* ws = (char*)d_ws;
  const size_t MB = 1024 * 1024;
  us_t* WqT = (us_t*)(ws + 0 * MB);
  us_t* WkT = (us_t*)(ws + 2 * MB);
  us_t* WvT = (us_t*)(ws + 4 * MB);
  us_t* WoT = (us_t*)(ws + 6 * MB);
  us_t* Qh  = (us_t*)(ws + 8 * MB);
  us_t* Kh  = (us_t*)(ws + 16 * MB);
  us_t* Vt  = (us_t*)(ws + 24 * MB);
  us_t* AO  = (us_t*)(ws + 32 * MB);

  dim3 tg(EMB / 32, EMB / 32);
  wtrans<<<tg, 256, 0, stream>>>(Wq, WqT);
  wtrans<<<tg, 256, 0, stream>>>(Wk, WkT);
  wtrans<<<tg, 256, 0, stream>>>(Wv, WvT);
  wtrans<<<tg, 256, 0, stream>>>(Wo, WoT);

  dim3 gg(EMB / 128, (NBATCH * S_LEN) / 64);   // (8, 64) = 512 blocks
  gemm64<0, float><<<gg, 256, 0, stream>>>(q, WqT, Qh);
  gemm64<0, float><<<gg, 256, 0, stream>>>(k, WkT, Kh);
  gemm64<1, float><<<gg, 256, 0, stream>>>(v, WvT, Vt);

  attn64<<<dim3(S_LEN / 64, NBATCH * NHEAD), 256, 0, stream>>>(Qh, Kh, Vt, AO);

  gemm64<2, us_t><<<gg, 256, 0, stream>>>(AO, WoT, out);
}

// Round 4
// 156.456 us; speedup vs baseline: 3.1933x; 1.1795x over previous
//
#include <hip/hip_runtime.h>
#include <type_traits>

#define S_LEN 2048
#define NHEAD 16
#define DHEAD 64
#define EMB   1024
#define NBATCH 2

typedef __bf16 bf16_t;
typedef bf16_t bf16x8 __attribute__((ext_vector_type(8)));
typedef float  f32x4  __attribute__((ext_vector_type(4)));
typedef unsigned short us_t;
typedef us_t   us8    __attribute__((ext_vector_type(8)));
typedef us_t   us4    __attribute__((ext_vector_type(4)));
typedef unsigned int u32x4 __attribute__((ext_vector_type(4)));

static __device__ __forceinline__ bf16x8 ld_bf16x8(const us_t* p) {
  return __builtin_bit_cast(bf16x8, *reinterpret_cast<const us8*>(p));
}
static __device__ __forceinline__ us_t f2bf(float f) {
  bf16_t h = (bf16_t)f;
  return __builtin_bit_cast(us_t, h);
}
// async global->LDS, 16B per lane. LDS dest = wave-uniform base + lane*16.
static __device__ __forceinline__ void gload16(const void* g, void* lds) {
  __builtin_amdgcn_global_load_lds((const __attribute__((address_space(1))) void*)g,
                                   (__attribute__((address_space(3))) void*)lds,
                                   16, 0, 0);
}

// ---------------- weight transpose + fp32->bf16 convert (4 weights, z-dim) --
__global__ __launch_bounds__(256) void wtrans4(const float* __restrict__ W0,
                                               const float* __restrict__ W1,
                                               const float* __restrict__ W2,
                                               const float* __restrict__ W3,
                                               us_t* __restrict__ O0,
                                               us_t* __restrict__ O1,
                                               us_t* __restrict__ O2,
                                               us_t* __restrict__ O3) {
  __shared__ float tile[32][33];
  const int z = blockIdx.z;
  const float* W = (z == 0) ? W0 : (z == 1) ? W1 : (z == 2) ? W2 : W3;
  us_t* WT = (z == 0) ? O0 : (z == 1) ? O1 : (z == 2) ? O2 : O3;
  const int n0 = blockIdx.x * 32, k0 = blockIdx.y * 32;
  const int tx = threadIdx.x & 31, ty = threadIdx.x >> 5;
#pragma unroll
  for (int i = 0; i < 32; i += 8)
    tile[ty + i][tx] = W[(size_t)(k0 + ty + i) * EMB + n0 + tx];
  __syncthreads();
#pragma unroll
  for (int i = 0; i < 32; i += 8)
    WT[(size_t)(n0 + ty + i) * EMB + k0 + tx] = f2bf(tile[tx][ty + i]);
}

// ---------------- merged projection GEMMs (q,k,v in one launch, z-dim) ------
// 64x128 tile, BK=32, 4 waves (2x2), global_load_lds double-buffered.
// z=0: Qh [(b*16+h)][s][d]; z=1: Kh same; z=2: Vt [(b*16+h)][d][s].
__global__ __launch_bounds__(256) void proj3(const float* __restrict__ A0,
                                             const float* __restrict__ A1,
                                             const float* __restrict__ A2,
                                             const us_t* __restrict__ B0,
                                             const us_t* __restrict__ B1,
                                             const us_t* __restrict__ B2,
                                             us_t* __restrict__ O0,
                                             us_t* __restrict__ O1,
                                             us_t* __restrict__ O2) {
  __shared__ char As[2][8192];
  __shared__ char Bs[2][8192];
  const int z = blockIdx.z;
  const float* A = (z == 0) ? A0 : (z == 1) ? A1 : A2;
  const us_t* BT = (z == 0) ? B0 : (z == 1) ? B1 : B2;
  us_t* O = (z == 0) ? O0 : (z == 1) ? O1 : O2;
  const bool vt_mode = (z == 2);

  const int lane = threadIdx.x & 63;
  const int wave = threadIdx.x >> 6;
  const int mt = blockIdx.y * 64;
  const int nt = blockIdx.x * 128;
  const int wm = ((wave >> 1) & 1) * 32;
  const int wn = (wave & 1) * 64;
  const int lr = lane & 15;
  const int lg = lane >> 4;

  f32x4 acc[2][4] = {};

  auto stage = [&](int buf, int k0) {
#pragma unroll
    for (int i = 0; i < 2; ++i) {
      const int seg = wave * 2 + i;
      const int r = seg * 8 + (lane >> 3);
      const int c16 = (lane & 7) ^ (lane >> 3);
      gload16((const char*)A + ((size_t)(mt + r) * EMB + k0) * 4 + c16 * 16,
              &As[buf][seg * 1024]);
    }
#pragma unroll
    for (int i = 0; i < 2; ++i) {
      const int seg = wave * 2 + i;
      const int r = seg * 16 + (lane >> 2);
      gload16((const char*)BT + ((size_t)(nt + r) * EMB + k0) * 2 + (lane & 3) * 16,
              &Bs[buf][seg * 1024]);
    }
  };

  stage(0, 0);
  __syncthreads();

  for (int ks = 0; ks < EMB / 32; ++ks) {
    const int cur = ks & 1;
    if (ks + 1 < EMB / 32) stage(cur ^ 1, (ks + 1) * 32);
    bf16x8 af[2], bfr[4];
#pragma unroll
    for (int i = 0; i < 2; ++i) {
      const int row = wm + 16 * i + lr;
      const char* rb = &As[cur][row * 128];
      f32x4 lo = *reinterpret_cast<const f32x4*>(rb + ((lg * 32) ^ ((lr & 7) << 4)));
      f32x4 hi = *reinterpret_cast<const f32x4*>(rb + ((lg * 32 + 16) ^ ((lr & 7) << 4)));
      bf16x8 t;
#pragma unroll
      for (int jj = 0; jj < 4; ++jj) { t[jj] = (bf16_t)lo[jj]; t[jj + 4] = (bf16_t)hi[jj]; }
      af[i] = t;
    }
#pragma unroll
    for (int j = 0; j < 4; ++j)
      bfr[j] = ld_bf16x8((const us_t*)&Bs[cur][(wn + 16 * j + lr) * 64 + lg * 16]);
#pragma unroll
    for (int i = 0; i < 2; ++i)
#pragma unroll
      for (int j = 0; j < 4; ++j)
        acc[i][j] = __builtin_amdgcn_mfma_f32_16x16x32_bf16(af[i], bfr[j], acc[i][j], 0, 0, 0);
    __syncthreads();
  }

  const int crow = (lane >> 4) * 4;
#pragma unroll
  for (int i = 0; i < 2; ++i)
#pragma unroll
    for (int j = 0; j < 4; ++j)
#pragma unroll
      for (int r = 0; r < 4; ++r) {
        const int m = mt + wm + 16 * i + crow + r;
        const int n = nt + wn + 16 * j + lr;
        const float val = acc[i][j][r];
        const int b = m >> 11, s = m & (S_LEN - 1);
        const int h = n >> 6, d = n & 63;
        if (!vt_mode)
          O[(((size_t)(b * NHEAD + h) * S_LEN + s) << 6) + d] = f2bf(val);
        else
          O[((size_t)(b * NHEAD + h) * DHEAD + d) * S_LEN + s] = f2bf(val);
      }
}

// ---------------- final GEMM: AO[M,1024] @ Wo -> fp32 out --------------------
__global__ __launch_bounds__(256) void gemmout(const us_t* __restrict__ A,
                                               const us_t* __restrict__ BT,
                                               float* __restrict__ O) {
  __shared__ char As[2][4096];
  __shared__ char Bs[2][8192];
  const int lane = threadIdx.x & 63;
  const int wave = threadIdx.x >> 6;
  const int mt = blockIdx.y * 64;
  const int nt = blockIdx.x * 128;
  const int wm = ((wave >> 1) & 1) * 32;
  const int wn = (wave & 1) * 64;
  const int lr = lane & 15;
  const int lg = lane >> 4;

  f32x4 acc[2][4] = {};

  auto stage = [&](int buf, int k0) {
    const int r = wave * 16 + (lane >> 2);
    gload16((const char*)A + ((size_t)(mt + r) * EMB + k0) * 2 + (lane & 3) * 16,
            &As[buf][wave * 1024]);
#pragma unroll
    for (int i = 0; i < 2; ++i) {
      const int seg = wave * 2 + i;
      const int rr = seg * 16 + (lane >> 2);
      gload16((const char*)BT + ((size_t)(nt + rr) * EMB + k0) * 2 + (lane & 3) * 16,
              &Bs[buf][seg * 1024]);
    }
  };

  stage(0, 0);
  __syncthreads();

  for (int ks = 0; ks < EMB / 32; ++ks) {
    const int cur = ks & 1;
    if (ks + 1 < EMB / 32) stage(cur ^ 1, (ks + 1) * 32);
    bf16x8 af[2], bfr[4];
#pragma unroll
    for (int i = 0; i < 2; ++i)
      af[i] = ld_bf16x8((const us_t*)&As[cur][(wm + 16 * i + lr) * 64 + lg * 16]);
#pragma unroll
    for (int j = 0; j < 4; ++j)
      bfr[j] = ld_bf16x8((const us_t*)&Bs[cur][(wn + 16 * j + lr) * 64 + lg * 16]);
#pragma unroll
    for (int i = 0; i < 2; ++i)
#pragma unroll
      for (int j = 0; j < 4; ++j)
        acc[i][j] = __builtin_amdgcn_mfma_f32_16x16x32_bf16(af[i], bfr[j], acc[i][j], 0, 0, 0);
    __syncthreads();
  }

  const int crow = (lane >> 4) * 4;
#pragma unroll
  for (int i = 0; i < 2; ++i)
#pragma unroll
    for (int j = 0; j < 4; ++j)
#pragma unroll
      for (int r = 0; r < 4; ++r)
        O[(size_t)(mt + wm + 16 * i + crow + r) * EMB + nt + wn + 16 * j + lr] =
            acc[i][j][r];
}

// ---------------- flash attention, swapped-QK^T (strictly-causal + [0,0]) ---
// Qh,Kh: bf16 [B*H][S][64]; Vt: bf16 [B*H][64][S]; AO: bf16 [B][S][H*64]
// S^T = K.Q^T so each lane owns one q-row: in-lane softmax, no per-iter
// shfl reductions; defer-max skip; P^T->B-frag via 16 shfl exchange;
// O^T = V^T.P^T. K/V LDS staging identical to prev round (verified).
__global__ __launch_bounds__(256, 3) void attn64(const us_t* __restrict__ Qh,
                                                 const us_t* __restrict__ Kh,
                                                 const us_t* __restrict__ Vt,
                                                 us_t* __restrict__ AO) {
  __shared__ char Ks[2][8192];
  __shared__ char Vs[2][8192];
  const int flat = blockIdx.y * 32 + blockIdx.x;
  const int bh = (flat & 7) * 4 + ((flat >> 3) & 3);   // same bh -> same XCD
  const int qt = 31 - (flat >> 5);                     // heavy-first
  const int lane = threadIdx.x & 63;
  const int wave = threadIdx.x >> 6;
  const int lr = lane & 15;
  const int lg = lane >> 4;
  const int q_glob = qt * 64 + wave * 16 + lr;         // this lane's q row

  // Q fragment (B-operand): col q=lr, k=d contiguous
  const us_t* qbase = Qh + ((size_t)bh * S_LEN + q_glob) * DHEAD;
  bf16x8 qf[2] = { ld_bf16x8(qbase + lg * 8), ld_bf16x8(qbase + 32 + lg * 8) };

  const us_t* kbase0 = Kh + (size_t)bh * S_LEN * DHEAD;
  const us_t* vbase0 = Vt + (size_t)bh * DHEAD * S_LEN;

  auto stage = [&](int buf, int t0) {
#pragma unroll
    for (int i = 0; i < 2; ++i) {
      const int seg = wave * 2 + i;
      const int r = seg * 8 + (lane >> 3);
      const int c16 = (lane & 7) ^ (lane >> 3);
      gload16(kbase0 + (size_t)(t0 + r) * DHEAD + c16 * 8, &Ks[buf][seg * 1024]);
      gload16(vbase0 + (size_t)r * S_LEN + t0 + c16 * 8, &Vs[buf][seg * 1024]);
    }
  };

  f32x4 oaccT[4] = {};          // O^T: d=16j+4lg+r, q=lr
  float mrow = -1e9f;           // running max, log2-scaled domain
  float lsum = 0.f;             // per-lane partial sum (this lane's t's)
  const float c = 0.045084220f; // (1/32) * log2(e)

  stage(0, 0);
  __syncthreads();

  for (int tt = 0; tt <= qt; ++tt) {
    const int cur = tt & 1;
    if (tt < qt) stage(cur ^ 1, (tt + 1) * 64);

    // ---- S^T = K.Q^T : sc[j] rows t=16j+4lg+r, col q=lr ----
    f32x4 sc[4] = {};
#pragma unroll
    for (int ks = 0; ks < 2; ++ks)
#pragma unroll
      for (int j = 0; j < 4; ++j) {
        bf16x8 ak = ld_bf16x8((const us_t*)&Ks[cur][(16 * j + lr) * 128 +
                              ((ks * 64 + lg * 16) ^ ((lr & 7) << 4))]);
        sc[j] = __builtin_amdgcn_mfma_f32_16x16x32_bf16(ak, qf[ks], sc[j], 0, 0, 0);
      }

    // ---- mask (diagonal tile only): keep t<q, plus [0,0] ----
    if (tt == qt) {
#pragma unroll
      for (int j = 0; j < 4; ++j)
#pragma unroll
        for (int r = 0; r < 4; ++r) {
          const int t_g = tt * 64 + 16 * j + 4 * lg + r;
          if (!((t_g < q_glob) || (q_glob == 0 && t_g == 0))) sc[j][r] = -1e30f;
        }
    }

    // ---- in-lane max; defer-max rescale (rarely taken) ----
    float mx = sc[0][0];
#pragma unroll
    for (int j = 0; j < 4; ++j)
#pragma unroll
      for (int r = 0; r < 4; ++r) mx = fmaxf(mx, sc[j][r]);
    const float mxc = mx * c;
    if (__any(mxc > mrow + 8.f)) {
      float mc = mxc;
      mc = fmaxf(mc, __shfl_xor(mc, 16, 64));
      mc = fmaxf(mc, __shfl_xor(mc, 32, 64));
      const float m2 = fmaxf(mrow, mc);
      const float alpha = exp2f(mrow - m2);
      lsum *= alpha;
#pragma unroll
      for (int j = 0; j < 4; ++j)
#pragma unroll
        for (int r = 0; r < 4; ++r) oaccT[j][r] *= alpha;
      mrow = m2;
    }

    // ---- p = exp2(s*c - m); pack bf16 pairs ----
    unsigned int pk[4][2];
    float ps = 0.f;
#pragma unroll
    for (int j = 0; j < 4; ++j) {
      float p0 = exp2f(__builtin_fmaf(sc[j][0], c, -mrow));
      float p1 = exp2f(__builtin_fmaf(sc[j][1], c, -mrow));
      float p2 = exp2f(__builtin_fmaf(sc[j][2], c, -mrow));
      float p3 = exp2f(__builtin_fmaf(sc[j][3], c, -mrow));
      ps += (p0 + p1) + (p2 + p3);
      pk[j][0] = (unsigned)f2bf(p0) | ((unsigned)f2bf(p1) << 16);
      pk[j][1] = (unsigned)f2bf(p2) | ((unsigned)f2bf(p3) << 16);
    }
    lsum += ps;

    // ---- exchange: P^T C-layout -> PV B-frag (t=ks*32+8lg+u, col q=lr) ----
    const int srcA = (2 * (lg & 1)) * 16 + lr;
    const int srcB = srcA + 16;
    const bool hi = (lg >> 1) != 0;   // lanes 32..63 take j=2ks+1
    u32x4 bw[2];
#pragma unroll
    for (int ks = 0; ks < 2; ++ks) {
      unsigned a0 = __shfl((int)pk[2 * ks][0], srcA, 64);
      unsigned a0b = __shfl((int)pk[2 * ks + 1][0], srcA, 64);
      unsigned a1 = __shfl((int)pk[2 * ks][1], srcA, 64);
      unsigned a1b = __shfl((int)pk[2 * ks + 1][1], srcA, 64);
      unsigned b0 = __shfl((int)pk[2 * ks][0], srcB, 64);
      unsigned b0b = __shfl((int)pk[2 * ks + 1][0], srcB, 64);
      unsigned b1 = __shfl((int)pk[2 * ks][1], srcB, 64);
      unsigned b1b = __shfl((int)pk[2 * ks + 1][1], srcB, 64);
      bw[ks][0] = hi ? a0b : a0;
      bw[ks][1] = hi ? a1b : a1;
      bw[ks][2] = hi ? b0b : b0;
      bw[ks][3] = hi ? b1b : b1;
    }

    // ---- O^T = V^T.P^T ----
#pragma unroll
    for (int ks = 0; ks < 2; ++ks) {
      bf16x8 pf = __builtin_bit_cast(bf16x8, bw[ks]);
#pragma unroll
      for (int j = 0; j < 4; ++j) {
        bf16x8 av = ld_bf16x8((const us_t*)&Vs[cur][(16 * j + lr) * 128 +
                              ((ks * 64 + lg * 16) ^ ((lr & 7) << 4))]);
        oaccT[j] = __builtin_amdgcn_mfma_f32_16x16x32_bf16(av, pf, oaccT[j], 0, 0, 0);
      }
    }
    __syncthreads();
  }

  // ---- finalize: cross-lane lsum, normalize, store O^T ----
  lsum += __shfl_xor(lsum, 16, 64);
  lsum += __shfl_xor(lsum, 32, 64);
  const float inv = 1.0f / lsum;
  const int b = bh >> 4, h = bh & 15;
  us_t* aout = AO + (size_t)(b * S_LEN + q_glob) * EMB + h * DHEAD;
#pragma unroll
  for (int j = 0; j < 4; ++j) {
    us4 w;
#pragma unroll
    for (int r = 0; r < 4; ++r) w[r] = f2bf(oaccT[j][r] * inv);
    *reinterpret_cast<us4*>(aout + 16 * j + 4 * lg) = w;
  }
}

// ---------------------------------------------------------------------------
extern "C" void kernel_launch(void* const* d_in, const int* in_sizes, int n_in,
                              void* d_out, int out_size, void* d_ws, size_t ws_size,
                              hipStream_t stream) {
  const float* q  = (const float*)d_in[0];
  const float* k  = (const float*)d_in[1];
  const float* v  = (const float*)d_in[2];
  const float* Wq = (const float*)d_in[3];
  const float* Wk = (const float*)d_in[4];
  const float* Wv = (const float*)d_in[5];
  const float* Wo = (const float*)d_in[6];
  float* out = (float*)d_out;

  char* ws = (char*)d_ws;
  const size_t MB = 1024 * 1024;
  us_t* WqT = (us_t*)(ws + 0 * MB);
  us_t* WkT = (us_t*)(ws + 2 * MB);
  us_t* WvT = (us_t*)(ws + 4 * MB);
  us_t* WoT = (us_t*)(ws + 6 * MB);
  us_t* Qh  = (us_t*)(ws + 8 * MB);
  us_t* Kh  = (us_t*)(ws + 16 * MB);
  us_t* Vt  = (us_t*)(ws + 24 * MB);
  us_t* AO  = (us_t*)(ws + 32 * MB);

  wtrans4<<<dim3(EMB / 32, EMB / 32, 4), 256, 0, stream>>>(Wq, Wk, Wv, Wo,
                                                           WqT, WkT, WvT, WoT);

  proj3<<<dim3(EMB / 128, (NBATCH * S_LEN) / 64, 3), 256, 0, stream>>>(
      q, k, v, WqT, WkT, WvT, Qh, Kh, Vt);

  attn64<<<dim3(S_LEN / 64, NBATCH * NHEAD), 256, 0, stream>>>(Qh, Kh, Vt, AO);

  gemmout<<<dim3(EMB / 128, (NBATCH * S_LEN) / 64), 256, 0, stream>>>(AO, WoT, out);
}

// Round 5
// 139.426 us; speedup vs baseline: 3.5834x; 1.1221x over previous
//
#include <hip/hip_runtime.h>
#include <type_traits>

#define S_LEN 2048
#define NHEAD 16
#define DHEAD 64
#define EMB   1024
#define NBATCH 2

typedef __bf16 bf16_t;
typedef bf16_t bf16x8 __attribute__((ext_vector_type(8)));
typedef float  f32x4  __attribute__((ext_vector_type(4)));
typedef unsigned short us_t;
typedef us_t   us8    __attribute__((ext_vector_type(8)));
typedef us_t   us4    __attribute__((ext_vector_type(4)));
typedef unsigned int u32x4 __attribute__((ext_vector_type(4)));

static __device__ __forceinline__ bf16x8 ld_bf16x8(const us_t* p) {
  return __builtin_bit_cast(bf16x8, *reinterpret_cast<const us8*>(p));
}
static __device__ __forceinline__ us_t f2bf(float f) {
  bf16_t h = (bf16_t)f;
  return __builtin_bit_cast(us_t, h);
}
// async global->LDS, 16B per lane. LDS dest = wave-uniform base + lane*16.
static __device__ __forceinline__ void gload16(const void* g, void* lds) {
  __builtin_amdgcn_global_load_lds((const __attribute__((address_space(1))) void*)g,
                                   (__attribute__((address_space(3))) void*)lds,
                                   16, 0, 0);
}

// ---------------- activation fp32->bf16 convert (q,k,v, z-dim) --------------
__global__ __launch_bounds__(256) void cvt3(const float* __restrict__ A0,
                                            const float* __restrict__ A1,
                                            const float* __restrict__ A2,
                                            us_t* __restrict__ O0,
                                            us_t* __restrict__ O1,
                                            us_t* __restrict__ O2) {
  const int z = blockIdx.z;
  const float* A = (z == 0) ? A0 : (z == 1) ? A1 : A2;
  us_t* O = (z == 0) ? O0 : (z == 1) ? O1 : O2;
  const size_t i = ((size_t)blockIdx.x * 256 + threadIdx.x) * 8;
  f32x4 lo = *reinterpret_cast<const f32x4*>(A + i);
  f32x4 hi = *reinterpret_cast<const f32x4*>(A + i + 4);
  us8 w;
#pragma unroll
  for (int j = 0; j < 4; ++j) { w[j] = f2bf(lo[j]); w[j + 4] = f2bf(hi[j]); }
  *reinterpret_cast<us8*>(O + i) = w;
}

// ---------------- weight transpose + fp32->bf16 convert (4 weights, z-dim) --
__global__ __launch_bounds__(256) void wtrans4(const float* __restrict__ W0,
                                               const float* __restrict__ W1,
                                               const float* __restrict__ W2,
                                               const float* __restrict__ W3,
                                               us_t* __restrict__ O0,
                                               us_t* __restrict__ O1,
                                               us_t* __restrict__ O2,
                                               us_t* __restrict__ O3) {
  __shared__ float tile[32][33];
  const int z = blockIdx.z;
  const float* W = (z == 0) ? W0 : (z == 1) ? W1 : (z == 2) ? W2 : W3;
  us_t* WT = (z == 0) ? O0 : (z == 1) ? O1 : (z == 2) ? O2 : O3;
  const int n0 = blockIdx.x * 32, k0 = blockIdx.y * 32;
  const int tx = threadIdx.x & 31, ty = threadIdx.x >> 5;
#pragma unroll
  for (int i = 0; i < 32; i += 8)
    tile[ty + i][tx] = W[(size_t)(k0 + ty + i) * EMB + n0 + tx];
  __syncthreads();
#pragma unroll
  for (int i = 0; i < 32; i += 8)
    WT[(size_t)(n0 + ty + i) * EMB + k0 + tx] = f2bf(tile[tx][ty + i]);
}

// ---------------- m97-style 128x128 GEMM core (bf16 A,B^T; BK=32) -----------
// 4 waves 2x2, each 64x64 (4x4 frags of 16x16x32). Double-buffered 32KB LDS,
// global_load_lds width 16, linear LDS layout (T2 null at 2-phase).
// Epilogue via functor-like template int MODE:
//   MODE 0: bf16 [(b*16+h)][s][d]   (Qh/Kh)
//   MODE 1: bf16 [(b*16+h)][d][s]   (Vt)
//   MODE 2: fp32 [m][n]
template<int MODE>
static __device__ __forceinline__ void gemm_core(const us_t* __restrict__ A,
                                                 const us_t* __restrict__ BT,
                                                 void* __restrict__ O,
                                                 int mt, int nt,
                                                 char (*As)[8192], char (*Bs)[8192]) {
  const int lane = threadIdx.x & 63;
  const int wave = threadIdx.x >> 6;
  const int wm = (wave >> 1) * 64;
  const int wn = (wave & 1) * 64;
  const int lr = lane & 15;
  const int lg = lane >> 4;

  f32x4 acc[4][4] = {};

  auto stage = [&](int buf, int k0) {
#pragma unroll
    for (int i = 0; i < 2; ++i) {
      const int seg = wave * 2 + i;            // 0..7
      const int r = seg * 16 + (lane >> 2);    // 0..127
      const int cb = (lane & 3) * 16;          // byte col within 64B row
      gload16((const char*)A + ((size_t)(mt * 128 + r) * EMB + k0) * 2 + cb,
              &As[buf][seg * 1024]);
      gload16((const char*)BT + ((size_t)(nt * 128 + r) * EMB + k0) * 2 + cb,
              &Bs[buf][seg * 1024]);
    }
  };

  stage(0, 0);
  __syncthreads();

  for (int ks = 0; ks < EMB / 32; ++ks) {
    const int cur = ks & 1;
    if (ks + 1 < EMB / 32) stage(cur ^ 1, (ks + 1) * 32);
    bf16x8 af[4], bfr[4];
#pragma unroll
    for (int i = 0; i < 4; ++i)
      af[i] = ld_bf16x8((const us_t*)&As[cur][(wm + 16 * i + lr) * 64 + lg * 16]);
#pragma unroll
    for (int j = 0; j < 4; ++j)
      bfr[j] = ld_bf16x8((const us_t*)&Bs[cur][(wn + 16 * j + lr) * 64 + lg * 16]);
#pragma unroll
    for (int i = 0; i < 4; ++i)
#pragma unroll
      for (int j = 0; j < 4; ++j)
        acc[i][j] = __builtin_amdgcn_mfma_f32_16x16x32_bf16(af[i], bfr[j], acc[i][j], 0, 0, 0);
    __syncthreads();
  }

  const int crow = (lane >> 4) * 4;
#pragma unroll
  for (int i = 0; i < 4; ++i)
#pragma unroll
    for (int j = 0; j < 4; ++j)
#pragma unroll
      for (int r = 0; r < 4; ++r) {
        const int m = mt * 128 + wm + 16 * i + crow + r;
        const int n = nt * 128 + wn + 16 * j + lr;
        const float val = acc[i][j][r];
        if constexpr (MODE == 2) {
          ((float*)O)[(size_t)m * EMB + n] = val;
        } else {
          us_t* o = (us_t*)O;
          const int b = m >> 11, s = m & (S_LEN - 1);
          const int h = n >> 6, d = n & 63;
          if constexpr (MODE == 0)
            o[(((size_t)(b * NHEAD + h) * S_LEN + s) << 6) + d] = f2bf(val);
          else
            o[((size_t)(b * NHEAD + h) * DHEAD + d) * S_LEN + s] = f2bf(val);
        }
      }
}

// merged projection GEMMs: flat grid 768, XCD-chunked (96 works/XCD, nt fastest)
__global__ __launch_bounds__(256) void proj3(const us_t* __restrict__ A0,
                                             const us_t* __restrict__ A1,
                                             const us_t* __restrict__ A2,
                                             const us_t* __restrict__ B0,
                                             const us_t* __restrict__ B1,
                                             const us_t* __restrict__ B2,
                                             us_t* __restrict__ O0,
                                             us_t* __restrict__ O1,
                                             us_t* __restrict__ O2) {
  __shared__ char As[2][8192];
  __shared__ char Bs[2][8192];
  const int f = blockIdx.x;
  const int w = (f & 7) * 96 + (f >> 3);     // XCD x owns works [96x, 96x+96)
  const int z = w >> 8;                       // /256
  const int rem = w & 255;
  const int mt = rem >> 3, nt = rem & 7;      // nt fastest: 8 blocks share A panel
  const us_t* A = (z == 0) ? A0 : (z == 1) ? A1 : A2;
  const us_t* BT = (z == 0) ? B0 : (z == 1) ? B1 : B2;
  us_t* O = (z == 0) ? O0 : (z == 1) ? O1 : O2;
  if (z < 2)
    gemm_core<0>(A, BT, O, mt, nt, As, Bs);
  else
    gemm_core<1>(A, BT, O, mt, nt, As, Bs);
}

// final GEMM: AO[4096,1024] @ Wo -> fp32; flat grid 256, XCD-chunked
__global__ __launch_bounds__(256) void gemmout(const us_t* __restrict__ A,
                                               const us_t* __restrict__ BT,
                                               float* __restrict__ O) {
  __shared__ char As[2][8192];
  __shared__ char Bs[2][8192];
  const int f = blockIdx.x;
  const int w = (f & 7) * 32 + (f >> 3);
  const int mt = w >> 3, nt = w & 7;
  gemm_core<2>(A, BT, O, mt, nt, As, Bs);
}

// ---------------- flash attention, swapped-QK^T (strictly-causal + [0,0]) ---
// Qh,Kh: bf16 [B*H][S][64]; Vt: bf16 [B*H][64][S]; AO: bf16 [B][S][H*64]
__global__ __launch_bounds__(256, 3) void attn64(const us_t* __restrict__ Qh,
                                                 const us_t* __restrict__ Kh,
                                                 const us_t* __restrict__ Vt,
                                                 us_t* __restrict__ AO) {
  __shared__ char Ks[2][8192];
  __shared__ char Vs[2][8192];
  const int flat = blockIdx.y * 32 + blockIdx.x;
  const int bh = (flat & 7) * 4 + ((flat >> 3) & 3);   // same bh -> same XCD
  const int qt = 31 - (flat >> 5);                     // heavy-first
  const int lane = threadIdx.x & 63;
  const int wave = threadIdx.x >> 6;
  const int lr = lane & 15;
  const int lg = lane >> 4;
  const int q_glob = qt * 64 + wave * 16 + lr;         // this lane's q row

  const us_t* qbase = Qh + ((size_t)bh * S_LEN + q_glob) * DHEAD;
  bf16x8 qf[2] = { ld_bf16x8(qbase + lg * 8), ld_bf16x8(qbase + 32 + lg * 8) };

  const us_t* kbase0 = Kh + (size_t)bh * S_LEN * DHEAD;
  const us_t* vbase0 = Vt + (size_t)bh * DHEAD * S_LEN;

  auto stage = [&](int buf, int t0) {
#pragma unroll
    for (int i = 0; i < 2; ++i) {
      const int seg = wave * 2 + i;
      const int r = seg * 8 + (lane >> 3);
      const int c16 = (lane & 7) ^ (lane >> 3);
      gload16(kbase0 + (size_t)(t0 + r) * DHEAD + c16 * 8, &Ks[buf][seg * 1024]);
      gload16(vbase0 + (size_t)r * S_LEN + t0 + c16 * 8, &Vs[buf][seg * 1024]);
    }
  };

  f32x4 oaccT[4] = {};          // O^T: d=16j+4lg+r, q=lr
  float mrow = -1e9f;           // running max, log2-scaled domain
  float lsum = 0.f;             // per-lane partial sum
  const float c = 0.045084220f; // (1/32) * log2(e)

  stage(0, 0);
  __syncthreads();

  for (int tt = 0; tt <= qt; ++tt) {
    const int cur = tt & 1;
    if (tt < qt) stage(cur ^ 1, (tt + 1) * 64);

    // ---- S^T = K.Q^T : sc[j] rows t=16j+4lg+r, col q=lr ----
    f32x4 sc[4] = {};
#pragma unroll
    for (int ks = 0; ks < 2; ++ks)
#pragma unroll
      for (int j = 0; j < 4; ++j) {
        bf16x8 ak = ld_bf16x8((const us_t*)&Ks[cur][(16 * j + lr) * 128 +
                              ((ks * 64 + lg * 16) ^ ((lr & 7) << 4))]);
        sc[j] = __builtin_amdgcn_mfma_f32_16x16x32_bf16(ak, qf[ks], sc[j], 0, 0, 0);
      }

    // ---- mask (diagonal tile only): keep t<q, plus [0,0] ----
    if (tt == qt) {
#pragma unroll
      for (int j = 0; j < 4; ++j)
#pragma unroll
        for (int r = 0; r < 4; ++r) {
          const int t_g = tt * 64 + 16 * j + 4 * lg + r;
          if (!((t_g < q_glob) || (q_glob == 0 && t_g == 0))) sc[j][r] = -1e30f;
        }
    }

    // ---- in-lane max; defer-max rescale (rarely taken) ----
    float mx = sc[0][0];
#pragma unroll
    for (int j = 0; j < 4; ++j)
#pragma unroll
      for (int r = 0; r < 4; ++r) mx = fmaxf(mx, sc[j][r]);
    const float mxc = mx * c;
    if (__any(mxc > mrow + 8.f)) {
      float mc = mxc;
      mc = fmaxf(mc, __shfl_xor(mc, 16, 64));
      mc = fmaxf(mc, __shfl_xor(mc, 32, 64));
      const float m2 = fmaxf(mrow, mc);
      const float alpha = exp2f(mrow - m2);
      lsum *= alpha;
#pragma unroll
      for (int j = 0; j < 4; ++j)
#pragma unroll
        for (int r = 0; r < 4; ++r) oaccT[j][r] *= alpha;
      mrow = m2;
    }

    // ---- p = exp2(s*c - m); pack bf16 pairs ----
    unsigned int pk[4][2];
    float ps = 0.f;
#pragma unroll
    for (int j = 0; j < 4; ++j) {
      float p0 = exp2f(__builtin_fmaf(sc[j][0], c, -mrow));
      float p1 = exp2f(__builtin_fmaf(sc[j][1], c, -mrow));
      float p2 = exp2f(__builtin_fmaf(sc[j][2], c, -mrow));
      float p3 = exp2f(__builtin_fmaf(sc[j][3], c, -mrow));
      ps += (p0 + p1) + (p2 + p3);
      pk[j][0] = (unsigned)f2bf(p0) | ((unsigned)f2bf(p1) << 16);
      pk[j][1] = (unsigned)f2bf(p2) | ((unsigned)f2bf(p3) << 16);
    }
    lsum += ps;

    // ---- exchange: P^T C-layout -> PV B-frag (t=ks*32+8lg+u, col q=lr) ----
    const int srcA = (2 * (lg & 1)) * 16 + lr;
    const int srcB = srcA + 16;
    const bool hi = (lg >> 1) != 0;
    u32x4 bw[2];
#pragma unroll
    for (int ks = 0; ks < 2; ++ks) {
      unsigned a0 = __shfl((int)pk[2 * ks][0], srcA, 64);
      unsigned a0b = __shfl((int)pk[2 * ks + 1][0], srcA, 64);
      unsigned a1 = __shfl((int)pk[2 * ks][1], srcA, 64);
      unsigned a1b = __shfl((int)pk[2 * ks + 1][1], srcA, 64);
      unsigned b0 = __shfl((int)pk[2 * ks][0], srcB, 64);
      unsigned b0b = __shfl((int)pk[2 * ks + 1][0], srcB, 64);
      unsigned b1 = __shfl((int)pk[2 * ks][1], srcB, 64);
      unsigned b1b = __shfl((int)pk[2 * ks + 1][1], srcB, 64);
      bw[ks][0] = hi ? a0b : a0;
      bw[ks][1] = hi ? a1b : a1;
      bw[ks][2] = hi ? b0b : b0;
      bw[ks][3] = hi ? b1b : b1;
    }

    // ---- O^T = V^T.P^T ----
#pragma unroll
    for (int ks = 0; ks < 2; ++ks) {
      bf16x8 pf = __builtin_bit_cast(bf16x8, bw[ks]);
#pragma unroll
      for (int j = 0; j < 4; ++j) {
        bf16x8 av = ld_bf16x8((const us_t*)&Vs[cur][(16 * j + lr) * 128 +
                              ((ks * 64 + lg * 16) ^ ((lr & 7) << 4))]);
        oaccT[j] = __builtin_amdgcn_mfma_f32_16x16x32_bf16(av, pf, oaccT[j], 0, 0, 0);
      }
    }
    __syncthreads();
  }

  // ---- finalize: cross-lane lsum, normalize, store O^T ----
  lsum += __shfl_xor(lsum, 16, 64);
  lsum += __shfl_xor(lsum, 32, 64);
  const float inv = 1.0f / lsum;
  const int b = bh >> 4, h = bh & 15;
  us_t* aout = AO + (size_t)(b * S_LEN + q_glob) * EMB + h * DHEAD;
#pragma unroll
  for (int j = 0; j < 4; ++j) {
    us4 w;
#pragma unroll
    for (int r = 0; r < 4; ++r) w[r] = f2bf(oaccT[j][r] * inv);
    *reinterpret_cast<us4*>(aout + 16 * j + 4 * lg) = w;
  }
}

// ---------------------------------------------------------------------------
extern "C" void kernel_launch(void* const* d_in, const int* in_sizes, int n_in,
                              void* d_out, int out_size, void* d_ws, size_t ws_size,
                              hipStream_t stream) {
  const float* q  = (const float*)d_in[0];
  const float* k  = (const float*)d_in[1];
  const float* v  = (const float*)d_in[2];
  const float* Wq = (const float*)d_in[3];
  const float* Wk = (const float*)d_in[4];
  const float* Wv = (const float*)d_in[5];
  const float* Wo = (const float*)d_in[6];
  float* out = (float*)d_out;

  char* ws = (char*)d_ws;
  const size_t MB = 1024 * 1024;
  us_t* WqT = (us_t*)(ws + 0 * MB);
  us_t* WkT = (us_t*)(ws + 2 * MB);
  us_t* WvT = (us_t*)(ws + 4 * MB);
  us_t* WoT = (us_t*)(ws + 6 * MB);
  us_t* Qh  = (us_t*)(ws + 8 * MB);
  us_t* Kh  = (us_t*)(ws + 16 * MB);
  us_t* Vt  = (us_t*)(ws + 24 * MB);
  us_t* AO  = (us_t*)(ws + 32 * MB);   // aliases Qb (dead by then)
  us_t* Qb  = (us_t*)(ws + 32 * MB);
  us_t* Kb  = (us_t*)(ws + 40 * MB);
  us_t* Vb  = (us_t*)(ws + 48 * MB);

  cvt3<<<dim3((NBATCH * S_LEN * EMB) / (256 * 8), 1, 3), 256, 0, stream>>>(
      q, k, v, Qb, Kb, Vb);
  wtrans4<<<dim3(EMB / 32, EMB / 32, 4), 256, 0, stream>>>(Wq, Wk, Wv, Wo,
                                                           WqT, WkT, WvT, WoT);

  proj3<<<768, 256, 0, stream>>>(Qb, Kb, Vb, WqT, WkT, WvT, Qh, Kh, Vt);

  attn64<<<dim3(S_LEN / 64, NBATCH * NHEAD), 256, 0, stream>>>(Qh, Kh, Vt, AO);

  gemmout<<<256, 256, 0, stream>>>(AO, WoT, out);
}

// Round 6
// 134.694 us; speedup vs baseline: 3.7093x; 1.0351x over previous
//
#include <hip/hip_runtime.h>
#include <type_traits>

#define S_LEN 2048
#define NHEAD 16
#define DHEAD 64
#define EMB   1024
#define NBATCH 2

typedef __bf16 bf16_t;
typedef bf16_t bf16x8 __attribute__((ext_vector_type(8)));
typedef float  f32x4  __attribute__((ext_vector_type(4)));
typedef unsigned short us_t;
typedef us_t   us8    __attribute__((ext_vector_type(8)));
typedef us_t   us4    __attribute__((ext_vector_type(4)));
typedef unsigned int u32x4 __attribute__((ext_vector_type(4)));
typedef unsigned int u32x2 __attribute__((ext_vector_type(2)));
typedef short  s16x4  __attribute__((ext_vector_type(4)));

static __device__ __forceinline__ bf16x8 ld_bf16x8(const us_t* p) {
  return __builtin_bit_cast(bf16x8, *reinterpret_cast<const us8*>(p));
}
static __device__ __forceinline__ us_t f2bf(float f) {
  bf16_t h = (bf16_t)f;
  return __builtin_bit_cast(us_t, h);
}
// async global->LDS, 16B per lane. LDS dest = wave-uniform base + lane*16.
static __device__ __forceinline__ void gload16(const void* g, void* lds) {
  __builtin_amdgcn_global_load_lds((const __attribute__((address_space(1))) void*)g,
                                   (__attribute__((address_space(3))) void*)lds,
                                   16, 0, 0);
}

// ---------------- activation fp32->bf16 convert (q,k,v, z-dim) --------------
__global__ __launch_bounds__(256) void cvt3(const float* __restrict__ A0,
                                            const float* __restrict__ A1,
                                            const float* __restrict__ A2,
                                            us_t* __restrict__ O0,
                                            us_t* __restrict__ O1,
                                            us_t* __restrict__ O2) {
  const int z = blockIdx.z;
  const float* A = (z == 0) ? A0 : (z == 1) ? A1 : A2;
  us_t* O = (z == 0) ? O0 : (z == 1) ? O1 : O2;
  const size_t i = ((size_t)blockIdx.x * 256 + threadIdx.x) * 8;
  f32x4 lo = *reinterpret_cast<const f32x4*>(A + i);
  f32x4 hi = *reinterpret_cast<const f32x4*>(A + i + 4);
  us8 w;
#pragma unroll
  for (int j = 0; j < 4; ++j) { w[j] = f2bf(lo[j]); w[j + 4] = f2bf(hi[j]); }
  *reinterpret_cast<us8*>(O + i) = w;
}

// ---------------- weight transpose + fp32->bf16 convert (4 weights, z-dim) --
__global__ __launch_bounds__(256) void wtrans4(const float* __restrict__ W0,
                                               const float* __restrict__ W1,
                                               const float* __restrict__ W2,
                                               const float* __restrict__ W3,
                                               us_t* __restrict__ O0,
                                               us_t* __restrict__ O1,
                                               us_t* __restrict__ O2,
                                               us_t* __restrict__ O3) {
  __shared__ float tile[32][33];
  const int z = blockIdx.z;
  const float* W = (z == 0) ? W0 : (z == 1) ? W1 : (z == 2) ? W2 : W3;
  us_t* WT = (z == 0) ? O0 : (z == 1) ? O1 : (z == 2) ? O2 : O3;
  const int n0 = blockIdx.x * 32, k0 = blockIdx.y * 32;
  const int tx = threadIdx.x & 31, ty = threadIdx.x >> 5;
#pragma unroll
  for (int i = 0; i < 32; i += 8)
    tile[ty + i][tx] = W[(size_t)(k0 + ty + i) * EMB + n0 + tx];
  __syncthreads();
#pragma unroll
  for (int i = 0; i < 32; i += 8)
    WT[(size_t)(n0 + ty + i) * EMB + k0 + tx] = f2bf(tile[tx][ty + i]);
}

// ---------------- m97-style 128x128 GEMM core (bf16 A,B^T; BK=32) -----------
//   MODE 0: bf16 [(b*16+h)][s][d]   (Qh/Kh)
//   MODE 1: bf16 [(b*16+h)][d][s]   (Vt)
//   MODE 2: fp32 [m][n]
template<int MODE>
static __device__ __forceinline__ void gemm_core(const us_t* __restrict__ A,
                                                 const us_t* __restrict__ BT,
                                                 void* __restrict__ O,
                                                 int mt, int nt,
                                                 char (*As)[8192], char (*Bs)[8192]) {
  const int lane = threadIdx.x & 63;
  const int wave = threadIdx.x >> 6;
  const int wm = (wave >> 1) * 64;
  const int wn = (wave & 1) * 64;
  const int lr = lane & 15;
  const int lg = lane >> 4;

  f32x4 acc[4][4] = {};

  auto stage = [&](int buf, int k0) {
#pragma unroll
    for (int i = 0; i < 2; ++i) {
      const int seg = wave * 2 + i;            // 0..7
      const int r = seg * 16 + (lane >> 2);    // 0..127
      const int cb = (lane & 3) * 16;          // byte col within 64B row
      gload16((const char*)A + ((size_t)(mt * 128 + r) * EMB + k0) * 2 + cb,
              &As[buf][seg * 1024]);
      gload16((const char*)BT + ((size_t)(nt * 128 + r) * EMB + k0) * 2 + cb,
              &Bs[buf][seg * 1024]);
    }
  };

  stage(0, 0);
  __syncthreads();

  for (int ks = 0; ks < EMB / 32; ++ks) {
    const int cur = ks & 1;
    if (ks + 1 < EMB / 32) stage(cur ^ 1, (ks + 1) * 32);
    bf16x8 af[4], bfr[4];
#pragma unroll
    for (int i = 0; i < 4; ++i)
      af[i] = ld_bf16x8((const us_t*)&As[cur][(wm + 16 * i + lr) * 64 + lg * 16]);
#pragma unroll
    for (int j = 0; j < 4; ++j)
      bfr[j] = ld_bf16x8((const us_t*)&Bs[cur][(wn + 16 * j + lr) * 64 + lg * 16]);
#pragma unroll
    for (int i = 0; i < 4; ++i)
#pragma unroll
      for (int j = 0; j < 4; ++j)
        acc[i][j] = __builtin_amdgcn_mfma_f32_16x16x32_bf16(af[i], bfr[j], acc[i][j], 0, 0, 0);
    __syncthreads();
  }

  const int crow = (lane >> 4) * 4;
#pragma unroll
  for (int i = 0; i < 4; ++i)
#pragma unroll
    for (int j = 0; j < 4; ++j)
#pragma unroll
      for (int r = 0; r < 4; ++r) {
        const int m = mt * 128 + wm + 16 * i + crow + r;
        const int n = nt * 128 + wn + 16 * j + lr;
        const float val = acc[i][j][r];
        if constexpr (MODE == 2) {
          ((float*)O)[(size_t)m * EMB + n] = val;
        } else {
          us_t* o = (us_t*)O;
          const int b = m >> 11, s = m & (S_LEN - 1);
          const int h = n >> 6, d = n & 63;
          if constexpr (MODE == 0)
            o[(((size_t)(b * NHEAD + h) * S_LEN + s) << 6) + d] = f2bf(val);
          else
            o[((size_t)(b * NHEAD + h) * DHEAD + d) * S_LEN + s] = f2bf(val);
        }
      }
}

// merged projection GEMMs: flat grid 768, XCD-chunked (96 works/XCD, nt fastest)
__global__ __launch_bounds__(256) void proj3(const us_t* __restrict__ A0,
                                             const us_t* __restrict__ A1,
                                             const us_t* __restrict__ A2,
                                             const us_t* __restrict__ B0,
                                             const us_t* __restrict__ B1,
                                             const us_t* __restrict__ B2,
                                             us_t* __restrict__ O0,
                                             us_t* __restrict__ O1,
                                             us_t* __restrict__ O2) {
  __shared__ char As[2][8192];
  __shared__ char Bs[2][8192];
  const int f = blockIdx.x;
  const int w = (f & 7) * 96 + (f >> 3);     // XCD x owns works [96x, 96x+96)
  const int z = w >> 8;                       // /256
  const int rem = w & 255;
  const int mt = rem >> 3, nt = rem & 7;      // nt fastest: 8 blocks share A panel
  const us_t* A = (z == 0) ? A0 : (z == 1) ? A1 : A2;
  const us_t* BT = (z == 0) ? B0 : (z == 1) ? B1 : B2;
  us_t* O = (z == 0) ? O0 : (z == 1) ? O1 : O2;
  if (z < 2)
    gemm_core<0>(A, BT, O, mt, nt, As, Bs);
  else
    gemm_core<1>(A, BT, O, mt, nt, As, Bs);
}

// final GEMM: AO[4096,1024] @ Wo -> fp32; flat grid 256, XCD-chunked
__global__ __launch_bounds__(256) void gemmout(const us_t* __restrict__ A,
                                               const us_t* __restrict__ BT,
                                               float* __restrict__ O) {
  __shared__ char As[2][8192];
  __shared__ char Bs[2][8192];
  const int f = blockIdx.x;
  const int w = (f & 7) * 32 + (f >> 3);
  const int mt = w >> 3, nt = w & 7;
  gemm_core<2>(A, BT, O, mt, nt, As, Bs);
}

// ---------------- flash attention, swapped-QK^T (strictly-causal + [0,0]) ---
// Qh,Kh: bf16 [B*H][S][64]; Vt: bf16 [B*H][64][S]; AO: bf16 [B][S][H*64]
// PV uses 16x16x16 MFMA: its B-frag layout (col=lane&15, k=4*lg+i) equals the
// swapped-QK^T C-layout, so packed P feeds PV directly — no lane exchange.
__global__ __launch_bounds__(256, 4) void attn64(const us_t* __restrict__ Qh,
                                                 const us_t* __restrict__ Kh,
                                                 const us_t* __restrict__ Vt,
                                                 us_t* __restrict__ AO) {
  __shared__ char Ks[2][8192];
  __shared__ char Vs[2][8192];
  const int flat = blockIdx.y * 32 + blockIdx.x;
  const int bh = (flat & 7) * 4 + ((flat >> 3) & 3);   // same bh -> same XCD
  const int qt = 31 - (flat >> 5);                     // heavy-first
  const int lane = threadIdx.x & 63;
  const int wave = threadIdx.x >> 6;
  const int lr = lane & 15;
  const int lg = lane >> 4;
  const int q_glob = qt * 64 + wave * 16 + lr;         // this lane's q row

  const us_t* qbase = Qh + ((size_t)bh * S_LEN + q_glob) * DHEAD;
  bf16x8 qf[2] = { ld_bf16x8(qbase + lg * 8), ld_bf16x8(qbase + 32 + lg * 8) };

  const us_t* kbase0 = Kh + (size_t)bh * S_LEN * DHEAD;
  const us_t* vbase0 = Vt + (size_t)bh * DHEAD * S_LEN;

  auto stage = [&](int buf, int t0) {
#pragma unroll
    for (int i = 0; i < 2; ++i) {
      const int seg = wave * 2 + i;
      const int r = seg * 8 + (lane >> 3);
      const int c16 = (lane & 7) ^ (lane >> 3);
      gload16(kbase0 + (size_t)(t0 + r) * DHEAD + c16 * 8, &Ks[buf][seg * 1024]);
      gload16(vbase0 + (size_t)r * S_LEN + t0 + c16 * 8, &Vs[buf][seg * 1024]);
    }
  };

  f32x4 oaccT[4] = {};          // O^T block jd: row d=16jd+4lg+reg, col q=lr
  float mrow = -1e9f;           // running max, log2-scaled domain
  float lsum = 0.f;             // per-lane partial sum
  const float c = 0.045084220f; // (1/32) * log2(e)

  stage(0, 0);
  __syncthreads();

  for (int tt = 0; tt <= qt; ++tt) {
    const int cur = tt & 1;
    if (tt < qt) stage(cur ^ 1, (tt + 1) * 64);

    // ---- S^T = K.Q^T : sc[j] rows t=16j+4lg+r, col q=lr ----
    f32x4 sc[4] = {};
#pragma unroll
    for (int ks = 0; ks < 2; ++ks)
#pragma unroll
      for (int j = 0; j < 4; ++j) {
        bf16x8 ak = ld_bf16x8((const us_t*)&Ks[cur][(16 * j + lr) * 128 +
                              ((ks * 64 + lg * 16) ^ ((lr & 7) << 4))]);
        sc[j] = __builtin_amdgcn_mfma_f32_16x16x32_bf16(ak, qf[ks], sc[j], 0, 0, 0);
      }

    // ---- mask (diagonal tile only): keep t<q, plus [0,0] ----
    if (tt == qt) {
#pragma unroll
      for (int j = 0; j < 4; ++j)
#pragma unroll
        for (int r = 0; r < 4; ++r) {
          const int t_g = tt * 64 + 16 * j + 4 * lg + r;
          if (!((t_g < q_glob) || (q_glob == 0 && t_g == 0))) sc[j][r] = -1e30f;
        }
    }

    // ---- in-lane max; defer-max rescale (rarely taken) ----
    float mx = sc[0][0];
#pragma unroll
    for (int j = 0; j < 4; ++j)
#pragma unroll
      for (int r = 0; r < 4; ++r) mx = fmaxf(mx, sc[j][r]);
    const float mxc = mx * c;
    if (__any(mxc > mrow + 8.f)) {
      float mc = mxc;
      mc = fmaxf(mc, __shfl_xor(mc, 16, 64));
      mc = fmaxf(mc, __shfl_xor(mc, 32, 64));
      const float m2 = fmaxf(mrow, mc);
      const float alpha = exp2f(mrow - m2);
      lsum *= alpha;
#pragma unroll
      for (int j = 0; j < 4; ++j)
#pragma unroll
        for (int r = 0; r < 4; ++r) oaccT[j][r] *= alpha;
      mrow = m2;
    }

    // ---- p = exp2(s*c - m); pack bf16 pairs ----
    unsigned int pk[4][2];
    float ps = 0.f;
#pragma unroll
    for (int j = 0; j < 4; ++j) {
      float p0 = exp2f(__builtin_fmaf(sc[j][0], c, -mrow));
      float p1 = exp2f(__builtin_fmaf(sc[j][1], c, -mrow));
      float p2 = exp2f(__builtin_fmaf(sc[j][2], c, -mrow));
      float p3 = exp2f(__builtin_fmaf(sc[j][3], c, -mrow));
      ps += (p0 + p1) + (p2 + p3);
      pk[j][0] = (unsigned)f2bf(p0) | ((unsigned)f2bf(p1) << 16);
      pk[j][1] = (unsigned)f2bf(p2) | ((unsigned)f2bf(p3) << 16);
    }
    lsum += ps;

#if __has_builtin(__builtin_amdgcn_mfma_f32_16x16x16bf16_1k)
    // ---- O^T += V^T.P^T via 16x16x16: P C-layout IS the B-frag layout ----
#pragma unroll
    for (int jk = 0; jk < 4; ++jk) {
      s16x4 pf = __builtin_bit_cast(s16x4, (u32x2){pk[jk][0], pk[jk][1]});
#pragma unroll
      for (int jd = 0; jd < 4; ++jd) {
        const int addr = (16 * jd + lr) * 128 + ((32 * jk + 8 * lg) ^ ((lr & 7) << 4));
        s16x4 av = __builtin_bit_cast(s16x4, *reinterpret_cast<const us4*>(&Vs[cur][addr]));
        oaccT[jd] = __builtin_amdgcn_mfma_f32_16x16x16bf16_1k(av, pf, oaccT[jd], 0, 0, 0);
      }
    }
#else
    // ---- fallback: exchange P^T C-layout -> 16x16x32 B-frag ----
    {
      const int srcA = (2 * (lg & 1)) * 16 + lr;
      const int srcB = srcA + 16;
      const bool hi = (lg >> 1) != 0;
      u32x4 bw[2];
#pragma unroll
      for (int ks = 0; ks < 2; ++ks) {
        unsigned a0 = __shfl((int)pk[2 * ks][0], srcA, 64);
        unsigned a0b = __shfl((int)pk[2 * ks + 1][0], srcA, 64);
        unsigned a1 = __shfl((int)pk[2 * ks][1], srcA, 64);
        unsigned a1b = __shfl((int)pk[2 * ks + 1][1], srcA, 64);
        unsigned b0 = __shfl((int)pk[2 * ks][0], srcB, 64);
        unsigned b0b = __shfl((int)pk[2 * ks + 1][0], srcB, 64);
        unsigned b1 = __shfl((int)pk[2 * ks][1], srcB, 64);
        unsigned b1b = __shfl((int)pk[2 * ks + 1][1], srcB, 64);
        bw[ks][0] = hi ? a0b : a0;
        bw[ks][1] = hi ? a1b : a1;
        bw[ks][2] = hi ? b0b : b0;
        bw[ks][3] = hi ? b1b : b1;
      }
#pragma unroll
      for (int ks = 0; ks < 2; ++ks) {
        bf16x8 pf = __builtin_bit_cast(bf16x8, bw[ks]);
#pragma unroll
        for (int j = 0; j < 4; ++j) {
          bf16x8 av = ld_bf16x8((const us_t*)&Vs[cur][(16 * j + lr) * 128 +
                                ((ks * 64 + lg * 16) ^ ((lr & 7) << 4))]);
          oaccT[j] = __builtin_amdgcn_mfma_f32_16x16x32_bf16(av, pf, oaccT[j], 0, 0, 0);
        }
      }
    }
#endif
    __syncthreads();
  }

  // ---- finalize: cross-lane lsum, normalize, store O^T ----
  lsum += __shfl_xor(lsum, 16, 64);
  lsum += __shfl_xor(lsum, 32, 64);
  const float inv = 1.0f / lsum;
  const int b = bh >> 4, h = bh & 15;
  us_t* aout = AO + (size_t)(b * S_LEN + q_glob) * EMB + h * DHEAD;
#pragma unroll
  for (int j = 0; j < 4; ++j) {
    us4 w;
#pragma unroll
    for (int r = 0; r < 4; ++r) w[r] = f2bf(oaccT[j][r] * inv);
    *reinterpret_cast<us4*>(aout + 16 * j + 4 * lg) = w;
  }
}

// ---------------------------------------------------------------------------
extern "C" void kernel_launch(void* const* d_in, const int* in_sizes, int n_in,
                              void* d_out, int out_size, void* d_ws, size_t ws_size,
                              hipStream_t stream) {
  const float* q  = (const float*)d_in[0];
  const float* k  = (const float*)d_in[1];
  const float* v  = (const float*)d_in[2];
  const float* Wq = (const float*)d_in[3];
  const float* Wk = (const float*)d_in[4];
  const float* Wv = (const float*)d_in[5];
  const float* Wo = (const float*)d_in[6];
  float* out = (float*)d_out;

  char* ws = (char*)d_ws;
  const size_t MB = 1024 * 1024;
  us_t* WqT = (us_t*)(ws + 0 * MB);
  us_t* WkT = (us_t*)(ws + 2 * MB);
  us_t* WvT = (us_t*)(ws + 4 * MB);
  us_t* WoT = (us_t*)(ws + 6 * MB);
  us_t* Qh  = (us_t*)(ws + 8 * MB);
  us_t* Kh  = (us_t*)(ws + 16 * MB);
  us_t* Vt  = (us_t*)(ws + 24 * MB);
  us_t* AO  = (us_t*)(ws + 32 * MB);   // aliases Qb (dead by then)
  us_t* Qb  = (us_t*)(ws + 32 * MB);
  us_t* Kb  = (us_t*)(ws + 40 * MB);
  us_t* Vb  = (us_t*)(ws + 48 * MB);

  cvt3<<<dim3((NBATCH * S_LEN * EMB) / (256 * 8), 1, 3), 256, 0, stream>>>(
      q, k, v, Qb, Kb, Vb);
  wtrans4<<<dim3(EMB / 32, EMB / 32, 4), 256, 0, stream>>>(Wq, Wk, Wv, Wo,
                                                           WqT, WkT, WvT, WoT);

  proj3<<<768, 256, 0, stream>>>(Qb, Kb, Vb, WqT, WkT, WvT, Qh, Kh, Vt);

  attn64<<<dim3(S_LEN / 64, NBATCH * NHEAD), 256, 0, stream>>>(Qh, Kh, Vt, AO);

  gemmout<<<256, 256, 0, stream>>>(AO, WoT, out);
}

// Round 8
// 130.554 us; speedup vs baseline: 3.8269x; 1.0317x over previous
//
#include <hip/hip_runtime.h>
#include <type_traits>

#define S_LEN 2048
#define NHEAD 16
#define DHEAD 64
#define EMB   1024
#define NBATCH 2

typedef __bf16 bf16_t;
typedef bf16_t bf16x8 __attribute__((ext_vector_type(8)));
typedef float  f32x4  __attribute__((ext_vector_type(4)));
typedef unsigned short us_t;
typedef us_t   us8    __attribute__((ext_vector_type(8)));
typedef us_t   us4    __attribute__((ext_vector_type(4)));
typedef unsigned int u32x4 __attribute__((ext_vector_type(4)));
typedef unsigned int u32x2 __attribute__((ext_vector_type(2)));
typedef short  s16x4  __attribute__((ext_vector_type(4)));

static __device__ __forceinline__ bf16x8 ld_bf16x8(const us_t* p) {
  return __builtin_bit_cast(bf16x8, *reinterpret_cast<const us8*>(p));
}
static __device__ __forceinline__ us_t f2bf(float f) {
  bf16_t h = (bf16_t)f;
  return __builtin_bit_cast(us_t, h);
}
// packed f32x2 -> bf16x2 (1 instr; RNE on gfx950)
static __device__ __forceinline__ unsigned cvt_pk_bf16(float lo, float hi) {
  unsigned r;
  asm("v_cvt_pk_bf16_f32 %0, %1, %2" : "=v"(r) : "v"(lo), "v"(hi));
  return r;
}
#if __has_builtin(__builtin_amdgcn_exp2f)
#define EXP2(x) __builtin_amdgcn_exp2f(x)
#else
#define EXP2(x) exp2f(x)
#endif
// async global->LDS, 16B per lane. LDS dest = wave-uniform base + lane*16.
static __device__ __forceinline__ void gload16(const void* g, void* lds) {
  __builtin_amdgcn_global_load_lds((const __attribute__((address_space(1))) void*)g,
                                   (__attribute__((address_space(3))) void*)lds,
                                   16, 0, 0);
}

// ---------------- prep: cvt (z=0..2, 2048 blocks) + wtrans (z=3..6, 1024) ---
__global__ __launch_bounds__(256) void prep(const float* __restrict__ q,
                                            const float* __restrict__ k,
                                            const float* __restrict__ v,
                                            const float* __restrict__ W0,
                                            const float* __restrict__ W1,
                                            const float* __restrict__ W2,
                                            const float* __restrict__ W3,
                                            us_t* __restrict__ Qb,
                                            us_t* __restrict__ Kb,
                                            us_t* __restrict__ Vb,
                                            us_t* __restrict__ T0,
                                            us_t* __restrict__ T1,
                                            us_t* __restrict__ T2,
                                            us_t* __restrict__ T3) {
  const int z = blockIdx.z;
  if (z < 3) {
    // 32 x 64 = 2048 blocks x 256 thr x 8 elem = 4,194,304 = 2*2048*1024
    const float* A = (z == 0) ? q : (z == 1) ? k : v;
    us_t* O = (z == 0) ? Qb : (z == 1) ? Kb : Vb;
    const int flat = blockIdx.y * 32 + blockIdx.x;
    const size_t i = ((size_t)flat * 256 + threadIdx.x) * 8;
    f32x4 lo = *reinterpret_cast<const f32x4*>(A + i);
    f32x4 hi = *reinterpret_cast<const f32x4*>(A + i + 4);
    us8 w;
#pragma unroll
    for (int j = 0; j < 4; ++j) { w[j] = f2bf(lo[j]); w[j + 4] = f2bf(hi[j]); }
    *reinterpret_cast<us8*>(O + i) = w;
  } else {
    if (blockIdx.y >= EMB / 32) return;   // wtrans needs only 32x32
    __shared__ float tile[32][33];
    const int zz = z - 3;
    const float* W = (zz == 0) ? W0 : (zz == 1) ? W1 : (zz == 2) ? W2 : W3;
    us_t* WT = (zz == 0) ? T0 : (zz == 1) ? T1 : (zz == 2) ? T2 : T3;
    const int n0 = blockIdx.x * 32, k0 = blockIdx.y * 32;
    const int tx = threadIdx.x & 31, ty = threadIdx.x >> 5;
#pragma unroll
    for (int i = 0; i < 32; i += 8)
      tile[ty + i][tx] = W[(size_t)(k0 + ty + i) * EMB + n0 + tx];
    __syncthreads();
#pragma unroll
    for (int i = 0; i < 32; i += 8)
      WT[(size_t)(n0 + ty + i) * EMB + k0 + tx] = f2bf(tile[tx][ty + i]);
  }
}

// ---------------- m97-style 128x128 GEMM core (bf16 A,B^T; BK=32) -----------
//   MODE 0: bf16 [(b*16+h)][s][d]   (Qh/Kh)
//   MODE 1: bf16 [(b*16+h)][d][s]   (Vt)
//   MODE 2: fp32 [m][n]
template<int MODE>
static __device__ __forceinline__ void gemm_core(const us_t* __restrict__ A,
                                                 const us_t* __restrict__ BT,
                                                 void* __restrict__ O,
                                                 int mt, int nt,
                                                 char (*As)[8192], char (*Bs)[8192]) {
  const int lane = threadIdx.x & 63;
  const int wave = threadIdx.x >> 6;
  const int wm = (wave >> 1) * 64;
  const int wn = (wave & 1) * 64;
  const int lr = lane & 15;
  const int lg = lane >> 4;

  f32x4 acc[4][4] = {};

  auto stage = [&](int buf, int k0) {
#pragma unroll
    for (int i = 0; i < 2; ++i) {
      const int seg = wave * 2 + i;            // 0..7
      const int r = seg * 16 + (lane >> 2);    // 0..127
      const int cb = (lane & 3) * 16;          // byte col within 64B row
      gload16((const char*)A + ((size_t)(mt * 128 + r) * EMB + k0) * 2 + cb,
              &As[buf][seg * 1024]);
      gload16((const char*)BT + ((size_t)(nt * 128 + r) * EMB + k0) * 2 + cb,
              &Bs[buf][seg * 1024]);
    }
  };

  stage(0, 0);
  __syncthreads();

  for (int ks = 0; ks < EMB / 32; ++ks) {
    const int cur = ks & 1;
    if (ks + 1 < EMB / 32) stage(cur ^ 1, (ks + 1) * 32);
    bf16x8 af[4], bfr[4];
#pragma unroll
    for (int i = 0; i < 4; ++i)
      af[i] = ld_bf16x8((const us_t*)&As[cur][(wm + 16 * i + lr) * 64 + lg * 16]);
#pragma unroll
    for (int j = 0; j < 4; ++j)
      bfr[j] = ld_bf16x8((const us_t*)&Bs[cur][(wn + 16 * j + lr) * 64 + lg * 16]);
#pragma unroll
    for (int i = 0; i < 4; ++i)
#pragma unroll
      for (int j = 0; j < 4; ++j)
        acc[i][j] = __builtin_amdgcn_mfma_f32_16x16x32_bf16(af[i], bfr[j], acc[i][j], 0, 0, 0);
    __syncthreads();
  }

  const int crow = (lane >> 4) * 4;
#pragma unroll
  for (int i = 0; i < 4; ++i)
#pragma unroll
    for (int j = 0; j < 4; ++j)
#pragma unroll
      for (int r = 0; r < 4; ++r) {
        const int m = mt * 128 + wm + 16 * i + crow + r;
        const int n = nt * 128 + wn + 16 * j + lr;
        const float val = acc[i][j][r];
        if constexpr (MODE == 2) {
          ((float*)O)[(size_t)m * EMB + n] = val;
        } else {
          us_t* o = (us_t*)O;
          const int b = m >> 11, s = m & (S_LEN - 1);
          const int h = n >> 6, d = n & 63;
          if constexpr (MODE == 0)
            o[(((size_t)(b * NHEAD + h) * S_LEN + s) << 6) + d] = f2bf(val);
          else
            o[((size_t)(b * NHEAD + h) * DHEAD + d) * S_LEN + s] = f2bf(val);
        }
      }
}

// merged projection GEMMs: flat grid 768, XCD-chunked (96 works/XCD, nt fastest)
__global__ __launch_bounds__(256) void proj3(const us_t* __restrict__ A0,
                                             const us_t* __restrict__ A1,
                                             const us_t* __restrict__ A2,
                                             const us_t* __restrict__ B0,
                                             const us_t* __restrict__ B1,
                                             const us_t* __restrict__ B2,
                                             us_t* __restrict__ O0,
                                             us_t* __restrict__ O1,
                                             us_t* __restrict__ O2) {
  __shared__ char As[2][8192];
  __shared__ char Bs[2][8192];
  const int f = blockIdx.x;
  const int w = (f & 7) * 96 + (f >> 3);     // XCD x owns works [96x, 96x+96)
  const int z = w >> 8;                       // /256
  const int rem = w & 255;
  const int mt = rem >> 3, nt = rem & 7;      // nt fastest: 8 blocks share A panel
  const us_t* A = (z == 0) ? A0 : (z == 1) ? A1 : A2;
  const us_t* BT = (z == 0) ? B0 : (z == 1) ? B1 : B2;
  us_t* O = (z == 0) ? O0 : (z == 1) ? O1 : O2;
  if (z < 2)
    gemm_core<0>(A, BT, O, mt, nt, As, Bs);
  else
    gemm_core<1>(A, BT, O, mt, nt, As, Bs);
}

// final GEMM: AO[4096,1024] @ Wo -> fp32; flat grid 256, XCD-chunked
__global__ __launch_bounds__(256) void gemmout(const us_t* __restrict__ A,
                                               const us_t* __restrict__ BT,
                                               float* __restrict__ O) {
  __shared__ char As[2][8192];
  __shared__ char Bs[2][8192];
  const int f = blockIdx.x;
  const int w = (f & 7) * 32 + (f >> 3);
  const int mt = w >> 3, nt = w & 7;
  gemm_core<2>(A, BT, O, mt, nt, As, Bs);
}

// ---------------- flash attention, swapped-QK^T (strictly-causal + [0,0]) ---
// Qh,Kh: bf16 [B*H][S][64]; Vt: bf16 [B*H][64][S]; AO: bf16 [B][S][H*64]
// PV uses 16x16x16 MFMA: its B-frag layout (col=lane&15, k=4*lg+i) equals the
// swapped-QK^T C-layout, so packed P feeds PV directly — no lane exchange.
__global__ __launch_bounds__(256, 4) void attn64(const us_t* __restrict__ Qh,
                                                 const us_t* __restrict__ Kh,
                                                 const us_t* __restrict__ Vt,
                                                 us_t* __restrict__ AO) {
  __shared__ char Ks[2][8192];
  __shared__ char Vs[2][8192];
  const int flat = blockIdx.y * 32 + blockIdx.x;
  const int bh = (flat & 7) * 4 + ((flat >> 3) & 3);   // same bh -> same XCD
  const int qt = 31 - (flat >> 5);                     // heavy-first
  const int lane = threadIdx.x & 63;
  const int wave = threadIdx.x >> 6;
  const int lr = lane & 15;
  const int lg = lane >> 4;
  const int q_glob = qt * 64 + wave * 16 + lr;         // this lane's q row

  const us_t* qbase = Qh + ((size_t)bh * S_LEN + q_glob) * DHEAD;
  bf16x8 qf[2] = { ld_bf16x8(qbase + lg * 8), ld_bf16x8(qbase + 32 + lg * 8) };

  const us_t* kbase0 = Kh + (size_t)bh * S_LEN * DHEAD;
  const us_t* vbase0 = Vt + (size_t)bh * DHEAD * S_LEN;

  // loop-invariant swizzled LDS byte offsets (SROA'd to VGPRs)
  int koff[8];
#pragma unroll
  for (int ks = 0; ks < 2; ++ks)
#pragma unroll
    for (int j = 0; j < 4; ++j)
      koff[ks * 4 + j] = (16 * j + lr) * 128 + ((ks * 64 + lg * 16) ^ ((lr & 7) << 4));
  int voff[16];
#pragma unroll
  for (int jk = 0; jk < 4; ++jk)
#pragma unroll
    for (int jd = 0; jd < 4; ++jd)
      voff[jk * 4 + jd] = (16 * jd + lr) * 128 + ((32 * jk + 8 * lg) ^ ((lr & 7) << 4));

  auto stage = [&](int buf, int t0) {
#pragma unroll
    for (int i = 0; i < 2; ++i) {
      const int seg = wave * 2 + i;
      const int r = seg * 8 + (lane >> 3);
      const int c16 = (lane & 7) ^ (lane >> 3);
      gload16(kbase0 + (size_t)(t0 + r) * DHEAD + c16 * 8, &Ks[buf][seg * 1024]);
      gload16(vbase0 + (size_t)r * S_LEN + t0 + c16 * 8, &Vs[buf][seg * 1024]);
    }
  };

  f32x4 oaccT[4] = {};          // O^T block jd: row d=16jd+4lg+reg, col q=lr
  float mrow = -1e9f;           // running max, log2-scaled domain
  float lsum = 0.f;             // per-lane partial sum
  const float c = 0.045084220f; // (1/32) * log2(e)

  stage(0, 0);
  __syncthreads();

  for (int tt = 0; tt <= qt; ++tt) {
    const int cur = tt & 1;
    if (tt < qt) stage(cur ^ 1, (tt + 1) * 64);

    // ---- S^T = K.Q^T : sc[j] rows t=16j+4lg+r, col q=lr ----
    f32x4 sc[4] = {};
    __builtin_amdgcn_s_setprio(1);
#pragma unroll
    for (int ks = 0; ks < 2; ++ks)
#pragma unroll
      for (int j = 0; j < 4; ++j) {
        bf16x8 ak = ld_bf16x8((const us_t*)&Ks[cur][koff[ks * 4 + j]]);
        sc[j] = __builtin_amdgcn_mfma_f32_16x16x32_bf16(ak, qf[ks], sc[j], 0, 0, 0);
      }
    __builtin_amdgcn_s_setprio(0);

    // ---- mask (diagonal tile only): keep t<q, plus [0,0] ----
    if (tt == qt) {
#pragma unroll
      for (int j = 0; j < 4; ++j)
#pragma unroll
        for (int r = 0; r < 4; ++r) {
          const int t_g = tt * 64 + 16 * j + 4 * lg + r;
          if (!((t_g < q_glob) || (q_glob == 0 && t_g == 0))) sc[j][r] = -1e30f;
        }
    }

    // ---- in-lane max; defer-max rescale (rarely taken) ----
    float mx = sc[0][0];
#pragma unroll
    for (int j = 0; j < 4; ++j)
#pragma unroll
      for (int r = 0; r < 4; ++r) mx = fmaxf(mx, sc[j][r]);
    const float mxc = mx * c;
    if (__any(mxc > mrow + 8.f)) {
      float mc = mxc;
      mc = fmaxf(mc, __shfl_xor(mc, 16, 64));
      mc = fmaxf(mc, __shfl_xor(mc, 32, 64));
      const float m2 = fmaxf(mrow, mc);
      const float alpha = EXP2(mrow - m2);
      lsum *= alpha;
#pragma unroll
      for (int j = 0; j < 4; ++j)
#pragma unroll
        for (int r = 0; r < 4; ++r) oaccT[j][r] *= alpha;
      mrow = m2;
    }

    // ---- p = exp2(s*c - m); pack bf16 pairs via v_cvt_pk_bf16_f32 ----
    unsigned int pk[4][2];
    float ps = 0.f;
#pragma unroll
    for (int j = 0; j < 4; ++j) {
      float p0 = EXP2(__builtin_fmaf(sc[j][0], c, -mrow));
      float p1 = EXP2(__builtin_fmaf(sc[j][1], c, -mrow));
      float p2 = EXP2(__builtin_fmaf(sc[j][2], c, -mrow));
      float p3 = EXP2(__builtin_fmaf(sc[j][3], c, -mrow));
      ps += (p0 + p1) + (p2 + p3);
      pk[j][0] = cvt_pk_bf16(p0, p1);
      pk[j][1] = cvt_pk_bf16(p2, p3);
    }
    lsum += ps;

    // ---- O^T += V^T.P^T via 16x16x16: P C-layout IS the B-frag layout ----
    __builtin_amdgcn_s_setprio(1);
#pragma unroll
    for (int jk = 0; jk < 4; ++jk) {
      s16x4 pf = __builtin_bit_cast(s16x4, (u32x2){pk[jk][0], pk[jk][1]});
#pragma unroll
      for (int jd = 0; jd < 4; ++jd) {
        s16x4 av = __builtin_bit_cast(s16x4,
            *reinterpret_cast<const us4*>(&Vs[cur][voff[jk * 4 + jd]]));
        oaccT[jd] = __builtin_amdgcn_mfma_f32_16x16x16bf16_1k(av, pf, oaccT[jd], 0, 0, 0);
      }
    }
    __builtin_amdgcn_s_setprio(0);
    __syncthreads();
  }

  // ---- finalize: cross-lane lsum, normalize, store O^T ----
  lsum += __shfl_xor(lsum, 16, 64);
  lsum += __shfl_xor(lsum, 32, 64);
  const float inv = 1.0f / lsum;
  const int b = bh >> 4, h = bh & 15;
  us_t* aout = AO + (size_t)(b * S_LEN + q_glob) * EMB + h * DHEAD;
#pragma unroll
  for (int j = 0; j < 4; ++j) {
    us4 w;
#pragma unroll
    for (int r = 0; r < 4; ++r) w[r] = f2bf(oaccT[j][r] * inv);
    *reinterpret_cast<us4*>(aout + 16 * j + 4 * lg) = w;
  }
}

// ---------------------------------------------------------------------------
extern "C" void kernel_launch(void* const* d_in, const int* in_sizes, int n_in,
                              void* d_out, int out_size, void* d_ws, size_t ws_size,
                              hipStream_t stream) {
  const float* q  = (const float*)d_in[0];
  const float* k  = (const float*)d_in[1];
  const float* v  = (const float*)d_in[2];
  const float* Wq = (const float*)d_in[3];
  const float* Wk = (const float*)d_in[4];
  const float* Wv = (const float*)d_in[5];
  const float* Wo = (const float*)d_in[6];
  float* out = (float*)d_out;

  char* ws = (char*)d_ws;
  const size_t MB = 1024 * 1024;
  us_t* WqT = (us_t*)(ws + 0 * MB);
  us_t* WkT = (us_t*)(ws + 2 * MB);
  us_t* WvT = (us_t*)(ws + 4 * MB);
  us_t* WoT = (us_t*)(ws + 6 * MB);
  us_t* Qh  = (us_t*)(ws + 8 * MB);
  us_t* Kh  = (us_t*)(ws + 16 * MB);
  us_t* Vt  = (us_t*)(ws + 24 * MB);
  us_t* AO  = (us_t*)(ws + 32 * MB);   // aliases Qb (dead by then)
  us_t* Qb  = (us_t*)(ws + 32 * MB);
  us_t* Kb  = (us_t*)(ws + 40 * MB);
  us_t* Vb  = (us_t*)(ws + 48 * MB);

  prep<<<dim3(32, 64, 7), 256, 0, stream>>>(q, k, v, Wq, Wk, Wv, Wo,
                                            Qb, Kb, Vb, WqT, WkT, WvT, WoT);

  proj3<<<768, 256, 0, stream>>>(Qb, Kb, Vb, WqT, WkT, WvT, Qh, Kh, Vt);

  attn64<<<dim3(S_LEN / 64, NBATCH * NHEAD), 256, 0, stream>>>(Qh, Kh, Vt, AO);

  gemmout<<<256, 256, 0, stream>>>(AO, WoT, out);
}